// Round 12
// baseline (685.949 us; speedup 1.0000x reference)
//
#include <hip/hip_runtime.h>
#include <hip/hip_fp16.h>

// Problem dims (fixed)
#define Bc 128   // batch
#define Tc 128   // timesteps
#define Nc 128   // driving series
#define Mc 256   // hidden
#define G4 1024  // 4*M

typedef _Float16 half8 __attribute__((ext_vector_type(8)));
typedef float f32x4 __attribute__((ext_vector_type(4)));
typedef unsigned u32x4 __attribute__((ext_vector_type(4)));

__device__ __forceinline__ float frcp(float x) {
#if __has_builtin(__builtin_amdgcn_rcpf)
  return __builtin_amdgcn_rcpf(x);
#else
  return 1.f / x;
#endif
}
__device__ __forceinline__ float fsig(float x) { return frcp(1.f + __expf(-x)); }
__device__ __forceinline__ float ftanh(float x) {
  float t = __expf(2.f * x);
  return 1.f - 2.f * frcp(t + 1.f);
}

// gfx950: offset:N must precede cache flags
#define LDX4CC(dst, ptr, OFF) \
  asm volatile("global_load_dwordx4 %0, %1, off offset:" #OFF " sc0 sc1" \
               : "=v"(dst) : "v"(ptr))
#define LDX4P(dst, ptr, OFF) \
  asm volatile("global_load_dwordx4 %0, %1, off offset:" #OFF \
               : "=v"(dst) : "v"(ptr))
#define ATOMSW(ptr, v_) \
  asm volatile("global_atomic_swap %0, %1, off" :: "v"(ptr), "v"(v_) : "memory")
#define STDWP(ptr, v_) \
  asm volatile("global_store_dword %0, %1, off" :: "v"(ptr), "v"(v_) : "memory")
#define VMCNT0 do { asm volatile("s_waitcnt vmcnt(0)" ::: "memory"); \
                    __builtin_amdgcn_sched_barrier(0); } while (0)

// ---------------------------------------------------------------------------
// k_prep (17219 blocks x 256):
//  bid<512      : pack Wh -> fp16 A-frags (gate-interleaved cols j'=4m+g,
//                 k-pair order (r2, r2+4) matching B-side u32 (m,m+4) pairs)
//  512..575     : hx2[0] = ~pack(fp16(h0))
//  576..8767    : zero hx2[1..128]   (primary sentinel slots)
//  8768..16959  : zero hxs[1..128]   (shadow sentinel slots)
//  16960..17218 : zero flags (done[8][129][4] 64B-spaced) + xcdtab
// All re-zeroed EVERY launch (graph replays re-run the whole sequence).
// ---------------------------------------------------------------------------
__global__ void k_prep(const float* __restrict__ Wh, const float* __restrict__ h0,
                       __half* __restrict__ wht, unsigned* __restrict__ hx2,
                       unsigned* __restrict__ hxs, unsigned* __restrict__ flags) {
  int bid = blockIdx.x;
  if (bid < 512) {
    int i = bid * 256 + threadIdx.x;       // u32 index in [0, 131072)
    int jt = i >> 11;
    int rem = i & 2047;
    int kt = rem >> 8;
    int rem2 = rem & 255;
    int lane = rem2 >> 2;
    int r2 = rem2 & 3;
    int jp = jt * 16 + (lane & 15);        // permuted col j'
    int g = jp & 3, mcol = jp >> 2;
    int j = g * 256 + mcol;                // original Wh column
    int mk0 = kt * 32 + (lane >> 4) * 8 + r2;   // k-pair (r2, r2+4)
    wht[(size_t)i * 2]     = __float2half(Wh[(size_t)mk0 * G4 + j]);
    wht[(size_t)i * 2 + 1] = __float2half(Wh[(size_t)(mk0 + 4) * G4 + j]);
  } else if (bid < 576) {
    int idx = (bid - 512) * 256 + threadIdx.x;   // 0..16383
    int b = idx >> 7, i = idx & 127;
    int a = i >> 2, d = i & 3;
    unsigned lo = __half_as_ushort(__float2half(h0[(size_t)b * Mc + 8 * a + d]));
    unsigned hi = __half_as_ushort(__float2half(h0[(size_t)b * Mc + 8 * a + d + 4]));
    hx2[idx] = ~(lo | (hi << 16));
  } else if (bid < 8768) {
    int idx = (bid - 576) * 256 + threadIdx.x;   // 0..2097151
    hx2[16384 + idx] = 0u;
  } else if (bid < 16960) {
    int idx = (bid - 8768) * 256 + threadIdx.x;  // 0..2097151
    hxs[idx] = 0u;
  } else {
    int idx = (bid - 16960) * 256 + threadIdx.x; // 0..66303
    if (idx < 66048 + 32) flags[idx] = 0u;
  }
}

// ---------------------------------------------------------------------------
// k_ux: PX[b][u][n] = exp(2*(sum_t X[b][t][n]*Ud[t][u] + bU[u]))
// ---------------------------------------------------------------------------
__global__ void k_ux(const float* __restrict__ X, const float* __restrict__ Ud,
                     const float* __restrict__ bU, float* __restrict__ PX) {
  __shared__ float Xl[Tc][Nc];  // 64KB
  int b = blockIdx.x;
  const float* Xb = X + (size_t)b * Tc * Nc;
  for (int i = threadIdx.x; i < Tc * Nc; i += 256) Xl[i >> 7][i & 127] = Xb[i];
  __syncthreads();
  int n = threadIdx.x & 127;
  int uh = __builtin_amdgcn_readfirstlane(threadIdx.x >> 7);
  for (int u0 = uh * 64; u0 < uh * 64 + 64; u0 += 8) {
    float acc[8];
#pragma unroll
    for (int i = 0; i < 8; i++) acc[i] = 0.f;
    for (int tt = 0; tt < Tc; ++tt) {
      float xv = Xl[tt][n];
#pragma unroll
      for (int i = 0; i < 8; i++) acc[i] += xv * Ud[tt * Tc + u0 + i];
    }
#pragma unroll
    for (int i = 0; i < 8; i++)
      PX[((size_t)b * Tc + (u0 + i)) * Nc + n] = __expf(2.f * (acc[i] + bU[u0 + i]));
  }
}

// ---------------------------------------------------------------------------
// k_xwx2: XWxP[t][b][j'] with j' = 4m+g. grid 512 = t(128) x bq(4), 256 thr.
// ---------------------------------------------------------------------------
__global__ __launch_bounds__(256, 2)
void k_xwx2(const float* __restrict__ X, const float* __restrict__ Wx,
            const float* __restrict__ bias, float* __restrict__ XWxP) {
  __shared__ float xl[32][Nc];  // 16KB
  int t = blockIdx.x >> 2;
  int b0 = (blockIdx.x & 3) * 32;
  for (int i = threadIdx.x; i < 32 * Nc; i += 256) {
    int row = i >> 7, n = i & 127;
    xl[row][n] = X[(size_t)(b0 + row) * Tc * Nc + (size_t)t * Nc + n];
  }
  __syncthreads();
  int m = threadIdx.x;
  float acc[32][4];
#pragma unroll
  for (int i = 0; i < 32; i++)
#pragma unroll
    for (int g = 0; g < 4; g++) acc[i][g] = 0.f;
  for (int n = 0; n < Nc; ++n) {
    float wi = Wx[(size_t)n * G4 + m];
    float wf = Wx[(size_t)n * G4 + 256 + m];
    float wg = Wx[(size_t)n * G4 + 512 + m];
    float wo = Wx[(size_t)n * G4 + 768 + m];
#pragma unroll
    for (int i = 0; i < 32; i++) {
      float xv = xl[i][n];
      acc[i][0] += xv * wi; acc[i][1] += xv * wf;
      acc[i][2] += xv * wg; acc[i][3] += xv * wo;
    }
  }
  float bi = bias[m], bf = bias[256 + m], bg = bias[512 + m], bo = bias[768 + m];
#pragma unroll
  for (int i = 0; i < 32; i++) {
    float4 o;
    o.x = acc[i][0] + bi; o.y = acc[i][1] + bf;
    o.z = acc[i][2] + bg; o.w = acc[i][3] + bo;
    *(float4*)(XWxP + ((size_t)t * Bc + b0 + i) * G4 + m * 4) = o;
  }
}

// ---------------------------------------------------------------------------
// k_scan: persistent LSTM scan, 32 blocks x 512 threads.
// FAST (same-XCD group, runtime-verified): SPECULATIVE data-is-flag on L2.
//   Consumer plain-loads h[t] first-touch (L1-cold -> L2) and checks the
//   ~pack sentinel; all-nonzero -> use, no waiting at all. Miss -> per-wave
//   fallback: lanes 0..3 atomic-poll the 4 per-producer flag lines, then
//   re-load from the SHADOW copy (first-touch -> no stale-L1; r4's bug was
//   re-reading the same address). Producer: dual-publish h (primary+shadow,
//   plain stores) -> vmcnt(0) -> barrier -> tid0 flag swap -> c stores.
// SLOW (any placement): r10's proven sc0sc1 data-is-flag protocol.
// ---------------------------------------------------------------------------
template <bool FAST>
__device__ __forceinline__ void scan_body(
    const __half* __restrict__ wht, const float* __restrict__ xwxp,
    unsigned* __restrict__ hx2, unsigned* __restrict__ hxs,
    __half* __restrict__ cx, const float* __restrict__ s0,
    unsigned* __restrict__ flags,
    int q, int grp, int tid, int lane, int lg, int b, int jt0, int m0) {
  // persistent A fragments: 64 VGPRs, loaded once
  half8 A0[8], A1[8];
#pragma unroll
  for (int kt = 0; kt < 8; ++kt) {
    A0[kt] = *(const half8*)(wht + ((size_t)(jt0 * 8 + kt) * 64 + lane) * 8);
    A1[kt] = *(const half8*)(wht + ((size_t)((jt0 + 1) * 8 + kt) * 64 + lane) * 8);
  }

  float c0 = s0[(size_t)b * Mc + m0];
  float c1 = s0[(size_t)b * Mc + m0 + 4];

  const char* hq  = (const char*)hx2 + ((size_t)b * 128 + lg * 4) * 4;         // read h[t] primary
  const char* hq2 = (const char*)hxs + ((size_t)b * 128 + lg * 4) * 4 - 65536; // shadow slot t (t>=1)
  char*       hs  = (char*)hx2 + ((size_t)16384 + b * 128 + jt0 * 2 + lg) * 4; // write primary t+1
  char*       hss = (char*)hxs + ((size_t)b * 128 + jt0 * 2 + lg) * 4;         // write shadow t+1
  const float* xq = xwxp + ((size_t)b) * G4 + jt0 * 16 + lg * 4;
  __half*      cq = cx + (size_t)b * Mc;
  unsigned* dn = flags + (size_t)grp * 129 * 64;   // done[t][q] at dn + t*64 + q*16

  f32x4 braw[8];

#pragma unroll 1
  for (int t = 0; t < 128; ++t) {
    // PIN: force A-frags register-resident
    asm volatile("" : "+v"(A0[0]), "+v"(A0[1]), "+v"(A0[2]), "+v"(A0[3]),
                      "+v"(A0[4]), "+v"(A0[5]), "+v"(A0[6]), "+v"(A0[7]));
    asm volatile("" : "+v"(A1[0]), "+v"(A1[1]), "+v"(A1[2]), "+v"(A1[3]),
                      "+v"(A1[4]), "+v"(A1[5]), "+v"(A1[6]), "+v"(A1[7]));

    // acc init (plain loads, L2)
    f32x4 acc0 = *(const f32x4*)(xq);
    f32x4 acc1 = *(const f32x4*)(xq + 16);

    if (FAST) {
      // speculative primary loads (first-touch per launch)
      LDX4P(braw[0], hq, 0);   LDX4P(braw[1], hq, 64);
      LDX4P(braw[2], hq, 128); LDX4P(braw[3], hq, 192);
      LDX4P(braw[4], hq, 256); LDX4P(braw[5], hq, 320);
      LDX4P(braw[6], hq, 384); LDX4P(braw[7], hq, 448);
      VMCNT0;
      unsigned mn = 0xFFFFFFFFu;
#pragma unroll
      for (int kt = 0; kt < 8; ++kt) {
        u32x4 u = __builtin_bit_cast(u32x4, braw[kt]);
        mn = min(mn, min(min(u.x, u.y), min(u.z, u.w)));
      }
      if (__builtin_expect(mn == 0u, 0)) {
        // per-wave fallback: poll the 4 per-producer flag lines (atomics
        // execute at L2 — never L1), then read the SHADOW copy (first touch)
        unsigned v = 1u;
#pragma unroll 1
        do {
          if (lane < 4)
            asm volatile("global_atomic_or %0, %1, %2, off sc0\n\t"
                         "s_waitcnt vmcnt(0)"
                         : "=v"(v) : "v"(dn + (size_t)t * 64 + lane * 16), "v"(0u)
                         : "memory");
        } while (!__all(v == 1u));
        __builtin_amdgcn_sched_barrier(0);
        LDX4P(braw[0], hq2, 0);   LDX4P(braw[1], hq2, 64);
        LDX4P(braw[2], hq2, 128); LDX4P(braw[3], hq2, 192);
        LDX4P(braw[4], hq2, 256); LDX4P(braw[5], hq2, 320);
        LDX4P(braw[6], hq2, 384); LDX4P(braw[7], hq2, 448);
        VMCNT0;
      }
    } else {
      // data-is-flag: poll sc0sc1 loads until every dword nonzero
      LDX4CC(braw[0], hq, 0);   LDX4CC(braw[1], hq, 64);
      LDX4CC(braw[2], hq, 128); LDX4CC(braw[3], hq, 192);
      LDX4CC(braw[4], hq, 256); LDX4CC(braw[5], hq, 320);
      LDX4CC(braw[6], hq, 384); LDX4CC(braw[7], hq, 448);
      for (;;) {
        VMCNT0;
        unsigned mn = 0xFFFFFFFFu;
#pragma unroll
        for (int kt = 0; kt < 8; ++kt) {
          u32x4 u = __builtin_bit_cast(u32x4, braw[kt]);
          mn = min(mn, min(min(u.x, u.y), min(u.z, u.w)));
        }
        if (__builtin_expect(mn != 0u, 1)) break;
        LDX4CC(braw[0], hq, 0);   LDX4CC(braw[1], hq, 64);
        LDX4CC(braw[2], hq, 128); LDX4CC(braw[3], hq, 192);
        LDX4CC(braw[4], hq, 256); LDX4CC(braw[5], hq, 320);
        LDX4CC(braw[6], hq, 384); LDX4CC(braw[7], hq, 448);
      }
    }

#pragma unroll
    for (int kt = 0; kt < 8; ++kt) {
      u32x4 u = ~__builtin_bit_cast(u32x4, braw[kt]);
      half8 Bf = __builtin_bit_cast(half8, u);
      acc0 = __builtin_amdgcn_mfma_f32_16x16x32_f16(A0[kt], Bf, acc0, 0, 0, 0);
      acc1 = __builtin_amdgcn_mfma_f32_16x16x32_f16(A1[kt], Bf, acc1, 0, 0, 0);
    }
    // gates: regs 0..3 = (i,f,g,o)
    float i0 = fsig(acc0[0]), f0 = fsig(acc0[1]);
    float g0 = ftanh(acc0[2]), o0 = fsig(acc0[3]);
    c0 = f0 * c0 + i0 * g0;
    float h0v = o0 * ftanh(c0);
    float i1 = fsig(acc1[0]), f1 = fsig(acc1[1]);
    float g1 = ftanh(acc1[2]), o1 = fsig(acc1[3]);
    c1 = f1 * c1 + i1 * g1;
    float h1v = o1 * ftanh(c1);

    unsigned pk = (unsigned)__half_as_ushort(__float2half(h0v)) |
                  ((unsigned)__half_as_ushort(__float2half(h1v)) << 16);
    if (FAST) {
      STDWP(hs, ~pk);                      // primary publish -> shared L2
      STDWP(hss, ~pk);                     // shadow publish (fallback source)
      VMCNT0;                              // data stores acked...
      __syncthreads();                     // ...by all waves
      if (tid == 0)
        ATOMSW(dn + (size_t)(t + 1) * 64 + q * 16, 1u);  // own flag line
      cq[m0]     = __float2half(c0);       // c off the critical path
      cq[m0 + 4] = __float2half(c1);
    } else {
      ATOMSW(hs, ~pk);                     // publish at coherence point
      cq[m0]     = __float2half(c0);
      cq[m0 + 4] = __float2half(c1);
    }

    hq += 65536; hq2 += 65536; hs += 65536; hss += 65536;
    xq += Bc * G4; cq += Bc * Mc;
  }
}

__global__ __launch_bounds__(512, 2)
void k_scan(const __half* __restrict__ wht, const float* __restrict__ xwxp,
            unsigned* __restrict__ hx2, unsigned* __restrict__ hxs,
            __half* __restrict__ cx, const float* __restrict__ s0,
            unsigned* __restrict__ flags) {
  int bid = blockIdx.x;                 // 32 blocks
  int q = bid >> 3, grp = bid & 7;
  int tid = threadIdx.x;
  int lane = tid & 63;
  int lb = lane & 15, lg = lane >> 4;
  int b = grp * 16 + lb;
  int jt0 = q * 16 + (tid >> 6) * 2;    // even
  int m0 = jt0 * 4 + lg;

  // placement handshake (r3-proven): fast iff all 4 group members share an XCD
  unsigned* xcdtab = flags + 66048;
  __shared__ int s_fast;
  if (tid == 0) {
    unsigned xcd;
    asm volatile("s_getreg_b32 %0, hwreg(HW_REG_XCC_ID)" : "=s"(xcd));
    asm volatile("global_store_dword %0, %1, off sc0 sc1"
                 :: "v"(xcdtab + bid), "v"(xcd + 1u) : "memory");
    unsigned ref = 0; int fast = 1;
#pragma unroll 1
    for (int k = 0; k < 4; ++k) {
      unsigned v;
      do {
        asm volatile("global_load_dword %0, %1, off sc0 sc1\n\t"
                     "s_waitcnt vmcnt(0)"
                     : "=v"(v) : "v"(xcdtab + (k * 8 + grp)) : "memory");
      } while (v == 0u);
      if (k == 0) ref = v; else fast &= (v == ref) ? 1 : 0;
    }
    s_fast = fast;
  }
  __syncthreads();

  if (s_fast)
    scan_body<true>(wht, xwxp, hx2, hxs, cx, s0, flags, q, grp, tid, lane, lg, b, jt0, m0);
  else
    scan_body<false>(wht, xwxp, hx2, hxs, cx, s0, flags, q, grp, tid, lane, lg, b, jt0, m0);
}

// ---------------------------------------------------------------------------
// k_wall2: Wall[t*B+b][u] = [h;c] @ Wd + bW.
// h read from hx2 (u32 = ~(h[m_lo]|h[m_lo+4]<<16), m_lo = 8*(k2>>2)+(k2&3));
// c read from cx (natural half2 pairs (2k2, 2k2+1)).
// ---------------------------------------------------------------------------
__global__ void k_wall2(const unsigned* __restrict__ Hxu, const __half2* __restrict__ Cx2,
                        const float* __restrict__ Wd, const float* __restrict__ bW,
                        float* __restrict__ Wall) {
  int r0 = blockIdx.x * 32;
  int wv = __builtin_amdgcn_readfirstlane(threadIdx.x >> 6);
  int lane = threadIdx.x & 63;
  int u2 = lane * 2;
  int rbase = r0 + wv * 8;
  float acc[8][2];
#pragma unroll
  for (int i = 0; i < 8; i++) { acc[i][0] = 0.f; acc[i][1] = 0.f; }
#pragma unroll 2
  for (int k2 = 0; k2 < 128; ++k2) {
    int m_lo = 8 * (k2 >> 2) + (k2 & 3);
    float2 wh0 = *(const float2*)(Wd + (size_t)m_lo * Tc + u2);
    float2 wh1 = *(const float2*)(Wd + (size_t)(m_lo + 4) * Tc + u2);
    float2 wc0 = *(const float2*)(Wd + (size_t)(Mc + 2 * k2) * Tc + u2);
    float2 wc1 = *(const float2*)(Wd + (size_t)(Mc + 2 * k2 + 1) * Tc + u2);
#pragma unroll
    for (int i = 0; i < 8; i++) {
      unsigned hraw = ~Hxu[(size_t)(rbase + i) * 128 + 16384 + k2];  // slot t+1
      __half2 hv = __builtin_bit_cast(__half2, hraw);
      __half2 cv = Cx2[(size_t)(rbase + i) * 128 + k2];
      float hlo = __low2float(hv), hhi = __high2float(hv);
      float clo = __low2float(cv), chi = __high2float(cv);
      acc[i][0] += hlo * wh0.x + hhi * wh1.x + clo * wc0.x + chi * wc1.x;
      acc[i][1] += hlo * wh0.y + hhi * wh1.y + clo * wc0.y + chi * wc1.y;
    }
  }
  float bw0 = bW[u2], bw1 = bW[u2 + 1];
#pragma unroll
  for (int i = 0; i < 8; i++) {
    float2 o; o.x = acc[i][0] + bw0; o.y = acc[i][1] + bw1;
    *(float2*)(Wall + (size_t)(rbase + i) * Tc + u2) = o;
  }
}

// ---------------------------------------------------------------------------
// k_attn: logits_n = sum_u (-2 v_u) / (A_u * P_un + 1); softmax; out = X*alpha
// ---------------------------------------------------------------------------
__global__ void k_attn(const float* __restrict__ Wall, const float* __restrict__ PX,
                       const float* __restrict__ vd, const float* __restrict__ X,
                       float* __restrict__ out) {
  __shared__ float4 av[Nc];
  __shared__ float v2s[Nc];
  __shared__ float red[2][8];
  int b = blockIdx.x & 127, tq = blockIdx.x >> 7;
  int n = threadIdx.x;           // 0..127
  int wv = n >> 6;
  float4 a;
  a.x = __expf(2.f * Wall[((size_t)(tq * 4 + 0) * Bc + b) * Tc + n]);
  a.y = __expf(2.f * Wall[((size_t)(tq * 4 + 1) * Bc + b) * Tc + n]);
  a.z = __expf(2.f * Wall[((size_t)(tq * 4 + 2) * Bc + b) * Tc + n]);
  a.w = __expf(2.f * Wall[((size_t)(tq * 4 + 3) * Bc + b) * Tc + n]);
  av[n] = a;
  v2s[n] = -2.f * vd[n];
  __syncthreads();
  const float* Pb = PX + (size_t)b * Tc * Nc;
  float e0 = 0.f, e1 = 0.f, e2 = 0.f, e3 = 0.f;
#pragma unroll 4
  for (int u = 0; u < Tc; ++u) {
    float P = Pb[(size_t)u * Nc + n];
    float4 au = av[u];
    float v2 = v2s[u];
    e0 = fmaf(v2, frcp(fmaf(au.x, P, 1.f)), e0);
    e1 = fmaf(v2, frcp(fmaf(au.y, P, 1.f)), e1);
    e2 = fmaf(v2, frcp(fmaf(au.z, P, 1.f)), e2);
    e3 = fmaf(v2, frcp(fmaf(au.w, P, 1.f)), e3);
  }
  float m0 = e0, m1 = e1, m2 = e2, m3 = e3;
#pragma unroll
  for (int off = 32; off > 0; off >>= 1) {
    m0 = fmaxf(m0, __shfl_xor(m0, off));
    m1 = fmaxf(m1, __shfl_xor(m1, off));
    m2 = fmaxf(m2, __shfl_xor(m2, off));
    m3 = fmaxf(m3, __shfl_xor(m3, off));
  }
  if ((n & 63) == 0) {
    red[wv][0] = m0; red[wv][1] = m1; red[wv][2] = m2; red[wv][3] = m3;
  }
  __syncthreads();
  m0 = fmaxf(red[0][0], red[1][0]);
  m1 = fmaxf(red[0][1], red[1][1]);
  m2 = fmaxf(red[0][2], red[1][2]);
  m3 = fmaxf(red[0][3], red[1][3]);
  float x0 = __expf(e0 - m0);
  float x1 = __expf(e1 - m1);
  float x2 = __expf(e2 - m2);
  float x3 = __expf(e3 - m3);
  float s0 = x0, s1 = x1, s2 = x2, s3 = x3;
#pragma unroll
  for (int off = 32; off > 0; off >>= 1) {
    s0 += __shfl_xor(s0, off);
    s1 += __shfl_xor(s1, off);
    s2 += __shfl_xor(s2, off);
    s3 += __shfl_xor(s3, off);
  }
  if ((n & 63) == 0) {
    red[wv][4] = s0; red[wv][5] = s1; red[wv][6] = s2; red[wv][7] = s3;
  }
  __syncthreads();
  s0 = red[0][4] + red[1][4];
  s1 = red[0][5] + red[1][5];
  s2 = red[0][6] + red[1][6];
  s3 = red[0][7] + red[1][7];
  size_t xi0 = ((size_t)b * Tc + tq * 4) * Nc + n;
  out[xi0]            = X[xi0]            * (x0 * frcp(s0));
  out[xi0 + Nc]       = X[xi0 + Nc]       * (x1 * frcp(s1));
  out[xi0 + 2 * Nc]   = X[xi0 + 2 * Nc]   * (x2 * frcp(s2));
  out[xi0 + 3 * Nc]   = X[xi0 + 3 * Nc]   * (x3 * frcp(s3));
}

extern "C" void kernel_launch(void* const* d_in, const int* in_sizes, int n_in,
                              void* d_out, int out_size, void* d_ws, size_t ws_size,
                              hipStream_t stream) {
  (void)in_sizes; (void)n_in; (void)out_size; (void)ws_size;
  const float* X  = (const float*)d_in[0];
  const float* h0 = (const float*)d_in[1];
  const float* s0 = (const float*)d_in[2];
  const float* Wx = (const float*)d_in[3];
  const float* Wh = (const float*)d_in[4];
  const float* bb = (const float*)d_in[5];
  const float* Wd = (const float*)d_in[6];
  const float* bW = (const float*)d_in[7];
  const float* Ud = (const float*)d_in[8];
  const float* bU = (const float*)d_in[9];
  const float* vd = (const float*)d_in[10];
  // d_in[11] = bv: softmax(x + const) == softmax(x), no effect on output.
  float* out = (float*)d_out;
  float* ws = (float*)d_ws;

  float* PX       = ws;                            //  2,097,152 f
  float* XWxP     = PX + 2097152;                  // 16,777,216 f
  unsigned* hx2   = (unsigned*)(XWxP + 16777216);  // 129*16384 u32 (primary)
  unsigned* hxs   = hx2 + 129 * 16384;             // 128*16384 u32 (shadow)
  __half* cx      = (__half*)(hxs + 128 * 16384);  // 128*32768 halves
  float* Wall     = (float*)(cx + 128 * 32768);    //  2,097,152 f
  __half* wht     = (__half*)(Wall + 2097152);     //   262,144 halves
  unsigned* flags = (unsigned*)(wht + 262144);     // 66048 done + 32 xcdtab
  // total ~106 MB (117 MB proven available in r1)

  k_prep<<<17219, 256, 0, stream>>>(Wh, h0, wht, hx2, hxs, flags);
  k_ux<<<Bc, 256, 0, stream>>>(X, Ud, bU, PX);
  k_xwx2<<<Tc * 4, 256, 0, stream>>>(X, Wx, bb, XWxP);
  k_scan<<<32, 512, 0, stream>>>(wht, XWxP, hx2, hxs, cx, s0, flags);
  k_wall2<<<(Tc * Bc) / 32, 256, 0, stream>>>(hx2, (const __half2*)cx, Wd, bW, Wall);
  k_attn<<<Bc * 32, 128, 0, stream>>>(Wall, PX, vd, X, out);
}

// Round 13
// 681.334 us; speedup vs baseline: 1.0068x; 1.0068x over previous
//
#include <hip/hip_runtime.h>
#include <hip/hip_fp16.h>

// Problem dims (fixed)
#define Bc 128   // batch
#define Tc 128   // timesteps
#define Nc 128   // driving series
#define Mc 256   // hidden
#define G4 1024  // 4*M

typedef _Float16 half8 __attribute__((ext_vector_type(8)));
typedef float f32x4 __attribute__((ext_vector_type(4)));
typedef unsigned u32x4 __attribute__((ext_vector_type(4)));

__device__ __forceinline__ float frcp(float x) {
#if __has_builtin(__builtin_amdgcn_rcpf)
  return __builtin_amdgcn_rcpf(x);
#else
  return 1.f / x;
#endif
}
__device__ __forceinline__ float fsig(float x) { return frcp(1.f + __expf(-x)); }
__device__ __forceinline__ float ftanh(float x) {
  float t = __expf(2.f * x);
  return 1.f - 2.f * frcp(t + 1.f);
}

// gfx950: offset:N must precede cache flags
#define LDX4CC(dst, ptr, OFF) \
  asm volatile("global_load_dwordx4 %0, %1, off offset:" #OFF " sc0 sc1" \
               : "=v"(dst) : "v"(ptr))
#define LDX4P(dst, ptr, OFF) \
  asm volatile("global_load_dwordx4 %0, %1, off offset:" #OFF \
               : "=v"(dst) : "v"(ptr))
#define ATOMSW(ptr, v_) \
  asm volatile("global_atomic_swap %0, %1, off" :: "v"(ptr), "v"(v_) : "memory")
#define STDWP(ptr, v_) \
  asm volatile("global_store_dword %0, %1, off" :: "v"(ptr), "v"(v_) : "memory")
#define VMCNT0 do { asm volatile("s_waitcnt vmcnt(0)" ::: "memory"); \
                    __builtin_amdgcn_sched_barrier(0); } while (0)

// ---------------------------------------------------------------------------
// k_prep (9027 blocks x 256):
//  bid<512    : pack Wh -> fp16 A-frags (gate-interleaved cols j'=4m+g,
//               k-pair order (r2, r2+4) matching B-side u32 (m,m+4) pairs)
//  512..575   : hx2[0] = ~pack(fp16(h0))
//  576..8767  : zero hx2[1..128]  (slow-path sentinel; re-zeroed EVERY launch)
//  8768..9026 : zero flags (done[8][129][4] on 64B-spaced lines) + xcdtab
// ---------------------------------------------------------------------------
__global__ void k_prep(const float* __restrict__ Wh, const float* __restrict__ h0,
                       __half* __restrict__ wht, unsigned* __restrict__ hx2,
                       unsigned* __restrict__ flags) {
  int bid = blockIdx.x;
  if (bid < 512) {
    int i = bid * 256 + threadIdx.x;       // u32 index in [0, 131072)
    int jt = i >> 11;
    int rem = i & 2047;
    int kt = rem >> 8;
    int rem2 = rem & 255;
    int lane = rem2 >> 2;
    int r2 = rem2 & 3;
    int jp = jt * 16 + (lane & 15);        // permuted col j'
    int g = jp & 3, mcol = jp >> 2;
    int j = g * 256 + mcol;                // original Wh column
    int mk0 = kt * 32 + (lane >> 4) * 8 + r2;   // k-pair (r2, r2+4)
    wht[(size_t)i * 2]     = __float2half(Wh[(size_t)mk0 * G4 + j]);
    wht[(size_t)i * 2 + 1] = __float2half(Wh[(size_t)(mk0 + 4) * G4 + j]);
  } else if (bid < 576) {
    int idx = (bid - 512) * 256 + threadIdx.x;   // 0..16383
    int b = idx >> 7, i = idx & 127;
    int a = i >> 2, d = i & 3;
    unsigned lo = __half_as_ushort(__float2half(h0[(size_t)b * Mc + 8 * a + d]));
    unsigned hi = __half_as_ushort(__float2half(h0[(size_t)b * Mc + 8 * a + d + 4]));
    hx2[idx] = ~(lo | (hi << 16));
  } else if (bid < 8768) {
    int idx = (bid - 576) * 256 + threadIdx.x;   // 0..2097151
    hx2[16384 + idx] = 0u;
  } else {
    int idx = (bid - 8768) * 256 + threadIdx.x;  // 0..66303
    if (idx < 66048 + 32) flags[idx] = 0u;
  }
}

// ---------------------------------------------------------------------------
// k_ux: PX[b][u][n] = exp(2*(sum_t X[b][t][n]*Ud[t][u] + bU[u]))
// ---------------------------------------------------------------------------
__global__ void k_ux(const float* __restrict__ X, const float* __restrict__ Ud,
                     const float* __restrict__ bU, float* __restrict__ PX) {
  __shared__ float Xl[Tc][Nc];  // 64KB
  int b = blockIdx.x;
  const float* Xb = X + (size_t)b * Tc * Nc;
  for (int i = threadIdx.x; i < Tc * Nc; i += 256) Xl[i >> 7][i & 127] = Xb[i];
  __syncthreads();
  int n = threadIdx.x & 127;
  int uh = __builtin_amdgcn_readfirstlane(threadIdx.x >> 7);
  for (int u0 = uh * 64; u0 < uh * 64 + 64; u0 += 8) {
    float acc[8];
#pragma unroll
    for (int i = 0; i < 8; i++) acc[i] = 0.f;
    for (int tt = 0; tt < Tc; ++tt) {
      float xv = Xl[tt][n];
#pragma unroll
      for (int i = 0; i < 8; i++) acc[i] += xv * Ud[tt * Tc + u0 + i];
    }
#pragma unroll
    for (int i = 0; i < 8; i++)
      PX[((size_t)b * Tc + (u0 + i)) * Nc + n] = __expf(2.f * (acc[i] + bU[u0 + i]));
  }
}

// ---------------------------------------------------------------------------
// k_xwx2: XWxP[t][b][j'] with j' = 4m+g. grid 512 = t(128) x bq(4), 256 thr.
// ---------------------------------------------------------------------------
__global__ __launch_bounds__(256, 2)
void k_xwx2(const float* __restrict__ X, const float* __restrict__ Wx,
            const float* __restrict__ bias, float* __restrict__ XWxP) {
  __shared__ float xl[32][Nc];  // 16KB
  int t = blockIdx.x >> 2;
  int b0 = (blockIdx.x & 3) * 32;
  for (int i = threadIdx.x; i < 32 * Nc; i += 256) {
    int row = i >> 7, n = i & 127;
    xl[row][n] = X[(size_t)(b0 + row) * Tc * Nc + (size_t)t * Nc + n];
  }
  __syncthreads();
  int m = threadIdx.x;
  float acc[32][4];
#pragma unroll
  for (int i = 0; i < 32; i++)
#pragma unroll
    for (int g = 0; g < 4; g++) acc[i][g] = 0.f;
  for (int n = 0; n < Nc; ++n) {
    float wi = Wx[(size_t)n * G4 + m];
    float wf = Wx[(size_t)n * G4 + 256 + m];
    float wg = Wx[(size_t)n * G4 + 512 + m];
    float wo = Wx[(size_t)n * G4 + 768 + m];
#pragma unroll
    for (int i = 0; i < 32; i++) {
      float xv = xl[i][n];
      acc[i][0] += xv * wi; acc[i][1] += xv * wf;
      acc[i][2] += xv * wg; acc[i][3] += xv * wo;
    }
  }
  float bi = bias[m], bf = bias[256 + m], bg = bias[512 + m], bo = bias[768 + m];
#pragma unroll
  for (int i = 0; i < 32; i++) {
    float4 o;
    o.x = acc[i][0] + bi; o.y = acc[i][1] + bf;
    o.z = acc[i][2] + bg; o.w = acc[i][3] + bo;
    *(float4*)(XWxP + ((size_t)t * Bc + b0 + i) * G4 + m * 4) = o;
  }
}

// ---------------------------------------------------------------------------
// k_scan: persistent LSTM scan, 32 blocks x 512 threads.
// FAST (same-XCD group, runtime-verified; r11 proved this at 417us):
//   r11's chain minus the flag-poll serialization. r11 had 32 pollers (8
//   waves x 4 blocks, lane0 each) doing atomic RMWs on ONE flag line ->
//   1600-3200cy/step of L2 same-line serialization. Now: done[grp][t][q]
//   on 4 SEPARATE 64B lines; producer tid0 swaps its OWN line (1 RMW);
//   consumer threads tid<4 spin (1 poller per line, atomic_or 0 = L2-
//   coherent read), everyone else waits at __syncthreads. Data path
//   unchanged: plain stores -> vmcnt(0) -> barrier -> flag; plain
//   first-touch loads after the poll barrier (L1-cold -> L2, proven).
// SLOW (any placement): r10's proven sc0sc1 data-is-flag protocol.
// ---------------------------------------------------------------------------
template <bool FAST>
__device__ __forceinline__ void scan_body(
    const __half* __restrict__ wht, const float* __restrict__ xwxp,
    unsigned* __restrict__ hx2, __half* __restrict__ cx,
    const float* __restrict__ s0, unsigned* __restrict__ flags,
    int q, int grp, int tid, int lane, int lg, int b, int jt0, int m0) {
  // persistent A fragments: 64 VGPRs, loaded once
  half8 A0[8], A1[8];
#pragma unroll
  for (int kt = 0; kt < 8; ++kt) {
    A0[kt] = *(const half8*)(wht + ((size_t)(jt0 * 8 + kt) * 64 + lane) * 8);
    A1[kt] = *(const half8*)(wht + ((size_t)((jt0 + 1) * 8 + kt) * 64 + lane) * 8);
  }

  float c0 = s0[(size_t)b * Mc + m0];
  float c1 = s0[(size_t)b * Mc + m0 + 4];

  const char* hq = (const char*)hx2 + ((size_t)b * 128 + lg * 4) * 4;         // read h[t]
  char*       hs = (char*)hx2 + ((size_t)16384 + b * 128 + jt0 * 2 + lg) * 4; // write h[t+1]
  const float* xq = xwxp + ((size_t)b) * G4 + jt0 * 16 + lg * 4;
  __half*      cq = cx + (size_t)b * Mc;
  unsigned* dn = flags + (size_t)grp * 129 * 64;   // done[t][q] at dn + t*64 + q*16

  f32x4 braw[8];

#pragma unroll 1
  for (int t = 0; t < 128; ++t) {
    // PIN: force A-frags register-resident
    asm volatile("" : "+v"(A0[0]), "+v"(A0[1]), "+v"(A0[2]), "+v"(A0[3]),
                      "+v"(A0[4]), "+v"(A0[5]), "+v"(A0[6]), "+v"(A0[7]));
    asm volatile("" : "+v"(A1[0]), "+v"(A1[1]), "+v"(A1[2]), "+v"(A1[3]),
                      "+v"(A1[4]), "+v"(A1[5]), "+v"(A1[6]), "+v"(A1[7]));

    // acc init (plain loads, L2)
    f32x4 acc0 = *(const f32x4*)(xq);
    f32x4 acc1 = *(const f32x4*)(xq + 16);

    if (FAST) {
      if (t > 0) {
        if (tid < 4) {           // 1 poller per producer flag line (wave 0)
          const unsigned* fp_ = dn + (size_t)t * 64 + tid * 16;
          unsigned v;
#pragma unroll 1
          do {
            asm volatile("global_atomic_or %0, %1, %2, off sc0\n\t"
                         "s_waitcnt vmcnt(0)"
                         : "=v"(v) : "v"(fp_), "v"(0u) : "memory");
          } while (v != 1u);
        }
        __syncthreads();
        __builtin_amdgcn_sched_barrier(0);
      }
      // data: plain loads — first-touch addresses, L1 cold -> L2 (coherent)
      LDX4P(braw[0], hq, 0);   LDX4P(braw[1], hq, 64);
      LDX4P(braw[2], hq, 128); LDX4P(braw[3], hq, 192);
      LDX4P(braw[4], hq, 256); LDX4P(braw[5], hq, 320);
      LDX4P(braw[6], hq, 384); LDX4P(braw[7], hq, 448);
      VMCNT0;
    } else {
      // data-is-flag: poll sc0sc1 loads until every dword nonzero
      LDX4CC(braw[0], hq, 0);   LDX4CC(braw[1], hq, 64);
      LDX4CC(braw[2], hq, 128); LDX4CC(braw[3], hq, 192);
      LDX4CC(braw[4], hq, 256); LDX4CC(braw[5], hq, 320);
      LDX4CC(braw[6], hq, 384); LDX4CC(braw[7], hq, 448);
      for (;;) {
        VMCNT0;
        unsigned mn = 0xFFFFFFFFu;
#pragma unroll
        for (int kt = 0; kt < 8; ++kt) {
          u32x4 u = __builtin_bit_cast(u32x4, braw[kt]);
          mn = min(mn, min(min(u.x, u.y), min(u.z, u.w)));
        }
        if (__builtin_expect(mn != 0u, 1)) break;
        LDX4CC(braw[0], hq, 0);   LDX4CC(braw[1], hq, 64);
        LDX4CC(braw[2], hq, 128); LDX4CC(braw[3], hq, 192);
        LDX4CC(braw[4], hq, 256); LDX4CC(braw[5], hq, 320);
        LDX4CC(braw[6], hq, 384); LDX4CC(braw[7], hq, 448);
      }
    }

#pragma unroll
    for (int kt = 0; kt < 8; ++kt) {
      u32x4 u = ~__builtin_bit_cast(u32x4, braw[kt]);
      half8 Bf = __builtin_bit_cast(half8, u);
      acc0 = __builtin_amdgcn_mfma_f32_16x16x32_f16(A0[kt], Bf, acc0, 0, 0, 0);
      acc1 = __builtin_amdgcn_mfma_f32_16x16x32_f16(A1[kt], Bf, acc1, 0, 0, 0);
    }
    // gates: regs 0..3 = (i,f,g,o)
    float i0 = fsig(acc0[0]), f0 = fsig(acc0[1]);
    float g0 = ftanh(acc0[2]), o0 = fsig(acc0[3]);
    c0 = f0 * c0 + i0 * g0;
    float h0v = o0 * ftanh(c0);
    float i1 = fsig(acc1[0]), f1 = fsig(acc1[1]);
    float g1 = ftanh(acc1[2]), o1 = fsig(acc1[3]);
    c1 = f1 * c1 + i1 * g1;
    float h1v = o1 * ftanh(c1);

    unsigned pk = (unsigned)__half_as_ushort(__float2half(h0v)) |
                  ((unsigned)__half_as_ushort(__float2half(h1v)) << 16);
    if (FAST) {
      STDWP(hs, ~pk);                      // plain store -> shared L2
      VMCNT0;                              // h stores acked by L2...
      __syncthreads();                     // ...for all waves
      if (tid == 0)
        ATOMSW(dn + (size_t)(t + 1) * 64 + q * 16, 1u);  // own flag line
      cq[m0]     = __float2half(c0);       // c off the critical path
      cq[m0 + 4] = __float2half(c1);
    } else {
      ATOMSW(hs, ~pk);                     // publish at coherence point
      cq[m0]     = __float2half(c0);
      cq[m0 + 4] = __float2half(c1);
    }

    hq += 65536; hs += 65536; xq += Bc * G4; cq += Bc * Mc;
  }
}

__global__ __launch_bounds__(512, 2)
void k_scan(const __half* __restrict__ wht, const float* __restrict__ xwxp,
            unsigned* __restrict__ hx2, __half* __restrict__ cx,
            const float* __restrict__ s0, unsigned* __restrict__ flags) {
  int bid = blockIdx.x;                 // 32 blocks
  int q = bid >> 3, grp = bid & 7;
  int tid = threadIdx.x;
  int lane = tid & 63;
  int lb = lane & 15, lg = lane >> 4;
  int b = grp * 16 + lb;
  int jt0 = q * 16 + (tid >> 6) * 2;    // even
  int m0 = jt0 * 4 + lg;

  // placement handshake (r3-proven): fast iff all 4 group members share an XCD
  unsigned* xcdtab = flags + 66048;
  __shared__ int s_fast;
  if (tid == 0) {
    unsigned xcd;
    asm volatile("s_getreg_b32 %0, hwreg(HW_REG_XCC_ID)" : "=s"(xcd));
    asm volatile("global_store_dword %0, %1, off sc0 sc1"
                 :: "v"(xcdtab + bid), "v"(xcd + 1u) : "memory");
    unsigned ref = 0; int fast = 1;
#pragma unroll 1
    for (int k = 0; k < 4; ++k) {
      unsigned v;
      do {
        asm volatile("global_load_dword %0, %1, off sc0 sc1\n\t"
                     "s_waitcnt vmcnt(0)"
                     : "=v"(v) : "v"(xcdtab + (k * 8 + grp)) : "memory");
      } while (v == 0u);
      if (k == 0) ref = v; else fast &= (v == ref) ? 1 : 0;
    }
    s_fast = fast;
  }
  __syncthreads();

  if (s_fast)
    scan_body<true>(wht, xwxp, hx2, cx, s0, flags, q, grp, tid, lane, lg, b, jt0, m0);
  else
    scan_body<false>(wht, xwxp, hx2, cx, s0, flags, q, grp, tid, lane, lg, b, jt0, m0);
}

// ---------------------------------------------------------------------------
// k_wall2: Wall[t*B+b][u] = [h;c] @ Wd + bW.
// h read from hx2 (u32 = ~(h[m_lo]|h[m_lo+4]<<16), m_lo = 8*(k2>>2)+(k2&3));
// c read from cx (natural half2 pairs (2k2, 2k2+1)).
// ---------------------------------------------------------------------------
__global__ void k_wall2(const unsigned* __restrict__ Hxu, const __half2* __restrict__ Cx2,
                        const float* __restrict__ Wd, const float* __restrict__ bW,
                        float* __restrict__ Wall) {
  int r0 = blockIdx.x * 32;
  int wv = __builtin_amdgcn_readfirstlane(threadIdx.x >> 6);
  int lane = threadIdx.x & 63;
  int u2 = lane * 2;
  int rbase = r0 + wv * 8;
  float acc[8][2];
#pragma unroll
  for (int i = 0; i < 8; i++) { acc[i][0] = 0.f; acc[i][1] = 0.f; }
#pragma unroll 2
  for (int k2 = 0; k2 < 128; ++k2) {
    int m_lo = 8 * (k2 >> 2) + (k2 & 3);
    float2 wh0 = *(const float2*)(Wd + (size_t)m_lo * Tc + u2);
    float2 wh1 = *(const float2*)(Wd + (size_t)(m_lo + 4) * Tc + u2);
    float2 wc0 = *(const float2*)(Wd + (size_t)(Mc + 2 * k2) * Tc + u2);
    float2 wc1 = *(const float2*)(Wd + (size_t)(Mc + 2 * k2 + 1) * Tc + u2);
#pragma unroll
    for (int i = 0; i < 8; i++) {
      unsigned hraw = ~Hxu[(size_t)(rbase + i) * 128 + 16384 + k2];  // slot t+1
      __half2 hv = __builtin_bit_cast(__half2, hraw);
      __half2 cv = Cx2[(size_t)(rbase + i) * 128 + k2];
      float hlo = __low2float(hv), hhi = __high2float(hv);
      float clo = __low2float(cv), chi = __high2float(cv);
      acc[i][0] += hlo * wh0.x + hhi * wh1.x + clo * wc0.x + chi * wc1.x;
      acc[i][1] += hlo * wh0.y + hhi * wh1.y + clo * wc0.y + chi * wc1.y;
    }
  }
  float bw0 = bW[u2], bw1 = bW[u2 + 1];
#pragma unroll
  for (int i = 0; i < 8; i++) {
    float2 o; o.x = acc[i][0] + bw0; o.y = acc[i][1] + bw1;
    *(float2*)(Wall + (size_t)(rbase + i) * Tc + u2) = o;
  }
}

// ---------------------------------------------------------------------------
// k_attn: logits_n = sum_u (-2 v_u) / (A_u * P_un + 1); softmax; out = X*alpha
// ---------------------------------------------------------------------------
__global__ void k_attn(const float* __restrict__ Wall, const float* __restrict__ PX,
                       const float* __restrict__ vd, const float* __restrict__ X,
                       float* __restrict__ out) {
  __shared__ float4 av[Nc];
  __shared__ float v2s[Nc];
  __shared__ float red[2][8];
  int b = blockIdx.x & 127, tq = blockIdx.x >> 7;
  int n = threadIdx.x;           // 0..127
  int wv = n >> 6;
  float4 a;
  a.x = __expf(2.f * Wall[((size_t)(tq * 4 + 0) * Bc + b) * Tc + n]);
  a.y = __expf(2.f * Wall[((size_t)(tq * 4 + 1) * Bc + b) * Tc + n]);
  a.z = __expf(2.f * Wall[((size_t)(tq * 4 + 2) * Bc + b) * Tc + n]);
  a.w = __expf(2.f * Wall[((size_t)(tq * 4 + 3) * Bc + b) * Tc + n]);
  av[n] = a;
  v2s[n] = -2.f * vd[n];
  __syncthreads();
  const float* Pb = PX + (size_t)b * Tc * Nc;
  float e0 = 0.f, e1 = 0.f, e2 = 0.f, e3 = 0.f;
#pragma unroll 4
  for (int u = 0; u < Tc; ++u) {
    float P = Pb[(size_t)u * Nc + n];
    float4 au = av[u];
    float v2 = v2s[u];
    e0 = fmaf(v2, frcp(fmaf(au.x, P, 1.f)), e0);
    e1 = fmaf(v2, frcp(fmaf(au.y, P, 1.f)), e1);
    e2 = fmaf(v2, frcp(fmaf(au.z, P, 1.f)), e2);
    e3 = fmaf(v2, frcp(fmaf(au.w, P, 1.f)), e3);
  }
  float m0 = e0, m1 = e1, m2 = e2, m3 = e3;
#pragma unroll
  for (int off = 32; off > 0; off >>= 1) {
    m0 = fmaxf(m0, __shfl_xor(m0, off));
    m1 = fmaxf(m1, __shfl_xor(m1, off));
    m2 = fmaxf(m2, __shfl_xor(m2, off));
    m3 = fmaxf(m3, __shfl_xor(m3, off));
  }
  if ((n & 63) == 0) {
    red[wv][0] = m0; red[wv][1] = m1; red[wv][2] = m2; red[wv][3] = m3;
  }
  __syncthreads();
  m0 = fmaxf(red[0][0], red[1][0]);
  m1 = fmaxf(red[0][1], red[1][1]);
  m2 = fmaxf(red[0][2], red[1][2]);
  m3 = fmaxf(red[0][3], red[1][3]);
  float x0 = __expf(e0 - m0);
  float x1 = __expf(e1 - m1);
  float x2 = __expf(e2 - m2);
  float x3 = __expf(e3 - m3);
  float s0 = x0, s1 = x1, s2 = x2, s3 = x3;
#pragma unroll
  for (int off = 32; off > 0; off >>= 1) {
    s0 += __shfl_xor(s0, off);
    s1 += __shfl_xor(s1, off);
    s2 += __shfl_xor(s2, off);
    s3 += __shfl_xor(s3, off);
  }
  if ((n & 63) == 0) {
    red[wv][4] = s0; red[wv][5] = s1; red[wv][6] = s2; red[wv][7] = s3;
  }
  __syncthreads();
  s0 = red[0][4] + red[1][4];
  s1 = red[0][5] + red[1][5];
  s2 = red[0][6] + red[1][6];
  s3 = red[0][7] + red[1][7];
  size_t xi0 = ((size_t)b * Tc + tq * 4) * Nc + n;
  out[xi0]            = X[xi0]            * (x0 * frcp(s0));
  out[xi0 + Nc]       = X[xi0 + Nc]       * (x1 * frcp(s1));
  out[xi0 + 2 * Nc]   = X[xi0 + 2 * Nc]   * (x2 * frcp(s2));
  out[xi0 + 3 * Nc]   = X[xi0 + 3 * Nc]   * (x3 * frcp(s3));
}

extern "C" void kernel_launch(void* const* d_in, const int* in_sizes, int n_in,
                              void* d_out, int out_size, void* d_ws, size_t ws_size,
                              hipStream_t stream) {
  (void)in_sizes; (void)n_in; (void)out_size; (void)ws_size;
  const float* X  = (const float*)d_in[0];
  const float* h0 = (const float*)d_in[1];
  const float* s0 = (const float*)d_in[2];
  const float* Wx = (const float*)d_in[3];
  const float* Wh = (const float*)d_in[4];
  const float* bb = (const float*)d_in[5];
  const float* Wd = (const float*)d_in[6];
  const float* bW = (const float*)d_in[7];
  const float* Ud = (const float*)d_in[8];
  const float* bU = (const float*)d_in[9];
  const float* vd = (const float*)d_in[10];
  // d_in[11] = bv: softmax(x + const) == softmax(x), no effect on output.
  float* out = (float*)d_out;
  float* ws = (float*)d_ws;

  float* PX       = ws;                            //  2,097,152 f
  float* XWxP     = PX + 2097152;                  // 16,777,216 f
  unsigned* hx2   = (unsigned*)(XWxP + 16777216);  // 129*16384 u32 (~h pairs)
  __half* cx      = (__half*)(hx2 + 129 * 16384);  // 128*32768 halves
  float* Wall     = (float*)(cx + 128 * 32768);    //  2,097,152 f
  __half* wht     = (__half*)(Wall + 2097152);     //   262,144 halves
  unsigned* flags = (unsigned*)(wht + 262144);     // 66048 done + 32 xcdtab
  // total ~101 MB

  k_prep<<<9027, 256, 0, stream>>>(Wh, h0, wht, hx2, flags);
  k_ux<<<Bc, 256, 0, stream>>>(X, Ud, bU, PX);
  k_xwx2<<<Tc * 4, 256, 0, stream>>>(X, Wx, bb, XWxP);
  k_scan<<<32, 512, 0, stream>>>(wht, XWxP, hx2, cx, s0, flags);
  k_wall2<<<(Tc * Bc) / 32, 256, 0, stream>>>(hx2, (const __half2*)cx, Wd, bW, Wall);
  k_attn<<<Bc * 32, 128, 0, stream>>>(Wall, PX, vd, X, out);
}

// Round 14
// 644.851 us; speedup vs baseline: 1.0637x; 1.0566x over previous
//
#include <hip/hip_runtime.h>
#include <hip/hip_fp16.h>

// Problem dims (fixed)
#define Bc 128   // batch
#define Tc 128   // timesteps
#define Nc 128   // driving series
#define Mc 256   // hidden
#define G4 1024  // 4*M

typedef _Float16 half8 __attribute__((ext_vector_type(8)));
typedef float f32x4 __attribute__((ext_vector_type(4)));
typedef unsigned u32x4 __attribute__((ext_vector_type(4)));

__device__ __forceinline__ float frcp(float x) {
#if __has_builtin(__builtin_amdgcn_rcpf)
  return __builtin_amdgcn_rcpf(x);
#else
  return 1.f / x;
#endif
}
__device__ __forceinline__ float fsig(float x) { return frcp(1.f + __expf(-x)); }
__device__ __forceinline__ float ftanh(float x) {
  float t = __expf(2.f * x);
  return 1.f - 2.f * frcp(t + 1.f);
}

// gfx950: offset:N must precede cache flags
#define LDX4CC(dst, ptr, OFF) \
  asm volatile("global_load_dwordx4 %0, %1, off offset:" #OFF " sc0 sc1" \
               : "=v"(dst) : "v"(ptr))
#define LDX4P(dst, ptr, OFF) \
  asm volatile("global_load_dwordx4 %0, %1, off offset:" #OFF \
               : "=v"(dst) : "v"(ptr))
#define ATOMSW(ptr, v_) \
  asm volatile("global_atomic_swap %0, %1, off" :: "v"(ptr), "v"(v_) : "memory")
#define STDWP(ptr, v_) \
  asm volatile("global_store_dword %0, %1, off" :: "v"(ptr), "v"(v_) : "memory")
#define VMCNT0 do { asm volatile("s_waitcnt vmcnt(0)" ::: "memory"); \
                    __builtin_amdgcn_sched_barrier(0); } while (0)

// ---------------------------------------------------------------------------
// k_prep (13121 blocks x 256):
//  [0,512)      : Wh -> wht fp16 A-frags (gate-interleaved cols j'=4m+g,
//                 k-pair order (r2, r2+4) matching h-side u32 (m,m+4) packs)
//  [512,768)    : Wx -> wxt fp16 A-frags (same col permutation, NATURAL k
//                 order — x B-frags are packed natural too)
//  [768,832)    : hx2[0] = ~pack(fp16(h0))
//  [832,9024)   : zero hx2[1..128]  (slow-path sentinel; every launch)
//  [9024,13120) : X -> XTp fp16 B-frags [t][b][kt][lg][p], natural k order
//  13120        : zero flags + xcdtab
// ---------------------------------------------------------------------------
__global__ void k_prep(const float* __restrict__ Wh, const float* __restrict__ Wx,
                       const float* __restrict__ X, const float* __restrict__ h0,
                       __half* __restrict__ wht, __half* __restrict__ wxt,
                       __half* __restrict__ xtp, unsigned* __restrict__ hx2,
                       unsigned* __restrict__ flags) {
  int bid = blockIdx.x;
  if (bid < 512) {
    int i = bid * 256 + threadIdx.x;       // u32 index in [0, 131072)
    int jt = i >> 11;
    int rem = i & 2047;
    int kt = rem >> 8;
    int rem2 = rem & 255;
    int lane = rem2 >> 2;
    int r2 = rem2 & 3;
    int jp = jt * 16 + (lane & 15);        // permuted col j'
    int g = jp & 3, mcol = jp >> 2;
    int j = g * 256 + mcol;                // original Wh column
    int mk0 = kt * 32 + (lane >> 4) * 8 + r2;   // k-pair (r2, r2+4)
    wht[(size_t)i * 2]     = __float2half(Wh[(size_t)mk0 * G4 + j]);
    wht[(size_t)i * 2 + 1] = __float2half(Wh[(size_t)(mk0 + 4) * G4 + j]);
  } else if (bid < 768) {
    int i = (bid - 512) * 256 + threadIdx.x;   // u32 index in [0, 65536)
    int jt = i >> 10;
    int rem = i & 1023;
    int kt = rem >> 8;
    int rem2 = rem & 255;
    int lane = rem2 >> 2;
    int r2 = rem2 & 3;
    int jp = jt * 16 + (lane & 15);
    int g = jp & 3, mcol = jp >> 2;
    int j = g * 256 + mcol;                // original Wx column
    int n0 = kt * 32 + (lane >> 4) * 8 + 2 * r2;   // natural k order
    wxt[(size_t)i * 2]     = __float2half(Wx[(size_t)n0 * G4 + j]);
    wxt[(size_t)i * 2 + 1] = __float2half(Wx[(size_t)(n0 + 1) * G4 + j]);
  } else if (bid < 832) {
    int idx = (bid - 768) * 256 + threadIdx.x;   // 0..16383
    int b = idx >> 7, i = idx & 127;
    int a = i >> 2, d = i & 3;
    unsigned lo = __half_as_ushort(__float2half(h0[(size_t)b * Mc + 8 * a + d]));
    unsigned hi = __half_as_ushort(__float2half(h0[(size_t)b * Mc + 8 * a + d + 4]));
    hx2[idx] = ~(lo | (hi << 16));
  } else if (bid < 9024) {
    int idx = (bid - 832) * 256 + threadIdx.x;   // 0..2097151
    hx2[16384 + idx] = 0u;
  } else if (bid < 13120) {
    int i = (bid - 9024) * 256 + threadIdx.x;    // u32 index in [0, 1048576)
    int t = i >> 13;
    int rem = i & 8191;
    int b = rem >> 6;
    int rem2 = rem & 63;
    int kt = rem2 >> 4;
    int r = rem2 & 15;
    int lg = r >> 2, r2 = r & 3;
    int n0 = kt * 32 + lg * 8 + 2 * r2;          // natural k order
    const float* xr = X + ((size_t)b * Tc + t) * Nc;
    xtp[(size_t)i * 2]     = __float2half(xr[n0]);
    xtp[(size_t)i * 2 + 1] = __float2half(xr[n0 + 1]);
  } else {
    for (int i = threadIdx.x; i < 16544; i += 256) flags[i] = 0u;
  }
}

// ---------------------------------------------------------------------------
// k_ux: PX[b][u][n] = exp(2*(sum_t X[b][t][n]*Ud[t][u] + bU[u]))
// ---------------------------------------------------------------------------
__global__ void k_ux(const float* __restrict__ X, const float* __restrict__ Ud,
                     const float* __restrict__ bU, float* __restrict__ PX) {
  __shared__ float Xl[Tc][Nc];  // 64KB
  int b = blockIdx.x;
  const float* Xb = X + (size_t)b * Tc * Nc;
  for (int i = threadIdx.x; i < Tc * Nc; i += 256) Xl[i >> 7][i & 127] = Xb[i];
  __syncthreads();
  int n = threadIdx.x & 127;
  int uh = __builtin_amdgcn_readfirstlane(threadIdx.x >> 7);
  for (int u0 = uh * 64; u0 < uh * 64 + 64; u0 += 8) {
    float acc[8];
#pragma unroll
    for (int i = 0; i < 8; i++) acc[i] = 0.f;
    for (int tt = 0; tt < Tc; ++tt) {
      float xv = Xl[tt][n];
#pragma unroll
      for (int i = 0; i < 8; i++) acc[i] += xv * Ud[tt * Tc + u0 + i];
    }
#pragma unroll
    for (int i = 0; i < 8; i++)
      PX[((size_t)b * Tc + (u0 + i)) * Nc + n] = __expf(2.f * (acc[i] + bU[u0 + i]));
  }
}

// ---------------------------------------------------------------------------
// k_scan: persistent LSTM scan, 32 blocks x 512 threads.
// r11-EXACT sync (measured 417us best): FAST = same-XCD L2 exchange (plain
// stores/first-touch loads; vmcnt+barrier+atomic_add flag; lane0-per-wave
// polls one flag line, waits count==4). SLOW = sc0sc1 data-is-flag.
// NEW: x@Wx folded in — Wx A-frags (wxt) + X B-frags (xtp) + bias acc-init
// replace the XWxP precompute (kills k_xwx2 + 128MB of HBM round-trip).
// ---------------------------------------------------------------------------
template <bool FAST>
__device__ __forceinline__ void scan_body(
    const __half* __restrict__ wht, const __half* __restrict__ wxt,
    const __half* __restrict__ xtp,
    unsigned* __restrict__ hx2, __half* __restrict__ cx,
    const float* __restrict__ s0, const float* __restrict__ bb,
    unsigned* __restrict__ flags,
    int q, int grp, int tid, int lane, int lg, int b, int jt0, int m0) {
  // persistent A fragments: Wh 64 VGPRs + Wx 32 VGPRs, loaded once
  half8 A0[8], A1[8];
#pragma unroll
  for (int kt = 0; kt < 8; ++kt) {
    A0[kt] = *(const half8*)(wht + ((size_t)(jt0 * 8 + kt) * 64 + lane) * 8);
    A1[kt] = *(const half8*)(wht + ((size_t)((jt0 + 1) * 8 + kt) * 64 + lane) * 8);
  }
  half8 Ax0[4], Ax1[4];
#pragma unroll
  for (int kt = 0; kt < 4; ++kt) {
    Ax0[kt] = *(const half8*)(wxt + ((size_t)(jt0 * 4 + kt) * 64 + lane) * 8);
    Ax1[kt] = *(const half8*)(wxt + ((size_t)((jt0 + 1) * 4 + kt) * 64 + lane) * 8);
  }
  // bias acc-init: regs 0..3 = gates (i,f,g,o) at m0 / m0+4
  f32x4 binit0, binit1;
  binit0[0] = bb[m0];       binit0[1] = bb[256 + m0];
  binit0[2] = bb[512 + m0]; binit0[3] = bb[768 + m0];
  binit1[0] = bb[m0 + 4];       binit1[1] = bb[256 + m0 + 4];
  binit1[2] = bb[512 + m0 + 4]; binit1[3] = bb[768 + m0 + 4];

  float c0 = s0[(size_t)b * Mc + m0];
  float c1 = s0[(size_t)b * Mc + m0 + 4];

  const char* hq = (const char*)hx2 + ((size_t)b * 128 + lg * 4) * 4;         // read h[t]
  char*       hs = (char*)hx2 + ((size_t)16384 + b * 128 + jt0 * 2 + lg) * 4; // write h[t+1]
  const char* xt = (const char*)xtp + (size_t)b * 256 + lg * 16;              // X B-frags
  __half*      cq = cx + (size_t)b * Mc;
  unsigned* flgp = flags + (size_t)grp * 129 * 16;   // flag[t] at flgp + t*16

  f32x4 braw[8];
  f32x4 bx0, bx1, bx2, bx3;

#pragma unroll 1
  for (int t = 0; t < 128; ++t) {
    // PIN: force all A-frags register-resident
    asm volatile("" : "+v"(A0[0]), "+v"(A0[1]), "+v"(A0[2]), "+v"(A0[3]),
                      "+v"(A0[4]), "+v"(A0[5]), "+v"(A0[6]), "+v"(A0[7]));
    asm volatile("" : "+v"(A1[0]), "+v"(A1[1]), "+v"(A1[2]), "+v"(A1[3]),
                      "+v"(A1[4]), "+v"(A1[5]), "+v"(A1[6]), "+v"(A1[7]));
    asm volatile("" : "+v"(Ax0[0]), "+v"(Ax0[1]), "+v"(Ax0[2]), "+v"(Ax0[3]),
                      "+v"(Ax1[0]), "+v"(Ax1[1]), "+v"(Ax1[2]), "+v"(Ax1[3]),
                      "+v"(binit0), "+v"(binit1));

    // x B-frags: independent of h — issue before the poll (plain, first-touch)
    LDX4P(bx0, xt, 0); LDX4P(bx1, xt, 64); LDX4P(bx2, xt, 128); LDX4P(bx3, xt, 192);

    if (FAST) {
      if (t > 0) {
        unsigned ret = 0u;
#pragma unroll 1
        do {
          if (lane == 0)
            asm volatile("global_atomic_or %0, %1, %2, off sc0\n\t"
                         "s_waitcnt vmcnt(0)"
                         : "=v"(ret) : "v"(flgp + t * 16), "v"(0u) : "memory");
          ret = __builtin_amdgcn_readfirstlane(ret);
        } while (ret < 4u);
        __builtin_amdgcn_sched_barrier(0);
      }
      // h data: plain loads — first-touch addresses, L1 cold -> L2 (coherent)
      LDX4P(braw[0], hq, 0);   LDX4P(braw[1], hq, 64);
      LDX4P(braw[2], hq, 128); LDX4P(braw[3], hq, 192);
      LDX4P(braw[4], hq, 256); LDX4P(braw[5], hq, 320);
      LDX4P(braw[6], hq, 384); LDX4P(braw[7], hq, 448);
      VMCNT0;
    } else {
      // data-is-flag: poll sc0sc1 loads until every dword nonzero
      LDX4CC(braw[0], hq, 0);   LDX4CC(braw[1], hq, 64);
      LDX4CC(braw[2], hq, 128); LDX4CC(braw[3], hq, 192);
      LDX4CC(braw[4], hq, 256); LDX4CC(braw[5], hq, 320);
      LDX4CC(braw[6], hq, 384); LDX4CC(braw[7], hq, 448);
      for (;;) {
        VMCNT0;
        unsigned mn = 0xFFFFFFFFu;
#pragma unroll
        for (int kt = 0; kt < 8; ++kt) {
          u32x4 u = __builtin_bit_cast(u32x4, braw[kt]);
          mn = min(mn, min(min(u.x, u.y), min(u.z, u.w)));
        }
        if (__builtin_expect(mn != 0u, 1)) break;
        LDX4CC(braw[0], hq, 0);   LDX4CC(braw[1], hq, 64);
        LDX4CC(braw[2], hq, 128); LDX4CC(braw[3], hq, 192);
        LDX4CC(braw[4], hq, 256); LDX4CC(braw[5], hq, 320);
        LDX4CC(braw[6], hq, 384); LDX4CC(braw[7], hq, 448);
      }
    }

    f32x4 acc0 = binit0, acc1 = binit1;
    // x part: K=128 (4 tiles, natural k order both sides)
    {
      half8 B0 = __builtin_bit_cast(half8, bx0);
      half8 B1 = __builtin_bit_cast(half8, bx1);
      half8 B2 = __builtin_bit_cast(half8, bx2);
      half8 B3 = __builtin_bit_cast(half8, bx3);
      acc0 = __builtin_amdgcn_mfma_f32_16x16x32_f16(Ax0[0], B0, acc0, 0, 0, 0);
      acc1 = __builtin_amdgcn_mfma_f32_16x16x32_f16(Ax1[0], B0, acc1, 0, 0, 0);
      acc0 = __builtin_amdgcn_mfma_f32_16x16x32_f16(Ax0[1], B1, acc0, 0, 0, 0);
      acc1 = __builtin_amdgcn_mfma_f32_16x16x32_f16(Ax1[1], B1, acc1, 0, 0, 0);
      acc0 = __builtin_amdgcn_mfma_f32_16x16x32_f16(Ax0[2], B2, acc0, 0, 0, 0);
      acc1 = __builtin_amdgcn_mfma_f32_16x16x32_f16(Ax1[2], B2, acc1, 0, 0, 0);
      acc0 = __builtin_amdgcn_mfma_f32_16x16x32_f16(Ax0[3], B3, acc0, 0, 0, 0);
      acc1 = __builtin_amdgcn_mfma_f32_16x16x32_f16(Ax1[3], B3, acc1, 0, 0, 0);
    }
    // h part: K=256 (8 tiles, (m,m+4)-pair order both sides)
#pragma unroll
    for (int kt = 0; kt < 8; ++kt) {
      u32x4 u = ~__builtin_bit_cast(u32x4, braw[kt]);
      half8 Bf = __builtin_bit_cast(half8, u);
      acc0 = __builtin_amdgcn_mfma_f32_16x16x32_f16(A0[kt], Bf, acc0, 0, 0, 0);
      acc1 = __builtin_amdgcn_mfma_f32_16x16x32_f16(A1[kt], Bf, acc1, 0, 0, 0);
    }
    // gates: regs 0..3 = (i,f,g,o)
    float i0 = fsig(acc0[0]), f0 = fsig(acc0[1]);
    float g0 = ftanh(acc0[2]), o0 = fsig(acc0[3]);
    c0 = f0 * c0 + i0 * g0;
    float h0v = o0 * ftanh(c0);
    float i1 = fsig(acc1[0]), f1 = fsig(acc1[1]);
    float g1 = ftanh(acc1[2]), o1 = fsig(acc1[3]);
    c1 = f1 * c1 + i1 * g1;
    float h1v = o1 * ftanh(c1);

    unsigned pk = (unsigned)__half_as_ushort(__float2half(h0v)) |
                  ((unsigned)__half_as_ushort(__float2half(h1v)) << 16);
    if (FAST) {
      STDWP(hs, ~pk);                      // plain store -> shared L2
      VMCNT0;                              // h stores acked by L2...
      __syncthreads();                     // ...for all waves
      if (tid == 0)
        asm volatile("global_atomic_add %0, %1, off"
                     :: "v"(flgp + (t + 1) * 16), "v"(1u) : "memory");
      cq[m0]     = __float2half(c0);       // c off the critical path
      cq[m0 + 4] = __float2half(c1);
    } else {
      ATOMSW(hs, ~pk);                     // publish at coherence point
      cq[m0]     = __float2half(c0);
      cq[m0 + 4] = __float2half(c1);
    }

    hq += 65536; hs += 65536; xt += 32768; cq += Bc * Mc;
  }
}

__global__ __launch_bounds__(512, 1)
void k_scan(const __half* __restrict__ wht, const __half* __restrict__ wxt,
            const __half* __restrict__ xtp,
            unsigned* __restrict__ hx2, __half* __restrict__ cx,
            const float* __restrict__ s0, const float* __restrict__ bb,
            unsigned* __restrict__ flags) {
  int bid = blockIdx.x;                 // 32 blocks
  int q = bid >> 3, grp = bid & 7;
  int tid = threadIdx.x;
  int lane = tid & 63;
  int lb = lane & 15, lg = lane >> 4;
  int b = grp * 16 + lb;
  int jt0 = q * 16 + (tid >> 6) * 2;    // even
  int m0 = jt0 * 4 + lg;

  // placement handshake (r3-proven): fast iff all 4 group members share an XCD
  unsigned* xcdtab = flags + 16512;
  __shared__ int s_fast;
  if (tid == 0) {
    unsigned xcd;
    asm volatile("s_getreg_b32 %0, hwreg(HW_REG_XCC_ID)" : "=s"(xcd));
    asm volatile("global_store_dword %0, %1, off sc0 sc1"
                 :: "v"(xcdtab + bid), "v"(xcd + 1u) : "memory");
    unsigned ref = 0; int fast = 1;
#pragma unroll 1
    for (int k = 0; k < 4; ++k) {
      unsigned v;
      do {
        asm volatile("global_load_dword %0, %1, off sc0 sc1\n\t"
                     "s_waitcnt vmcnt(0)"
                     : "=v"(v) : "v"(xcdtab + (k * 8 + grp)) : "memory");
      } while (v == 0u);
      if (k == 0) ref = v; else fast &= (v == ref) ? 1 : 0;
    }
    s_fast = fast;
  }
  __syncthreads();

  if (s_fast)
    scan_body<true>(wht, wxt, xtp, hx2, cx, s0, bb, flags, q, grp, tid, lane, lg, b, jt0, m0);
  else
    scan_body<false>(wht, wxt, xtp, hx2, cx, s0, bb, flags, q, grp, tid, lane, lg, b, jt0, m0);
}

// ---------------------------------------------------------------------------
// k_wall2: Wall[t*B+b][u] = [h;c] @ Wd + bW.
// h read from hx2 (u32 = ~(h[m_lo]|h[m_lo+4]<<16), m_lo = 8*(k2>>2)+(k2&3));
// c read from cx (natural half2 pairs (2k2, 2k2+1)).
// ---------------------------------------------------------------------------
__global__ void k_wall2(const unsigned* __restrict__ Hxu, const __half2* __restrict__ Cx2,
                        const float* __restrict__ Wd, const float* __restrict__ bW,
                        float* __restrict__ Wall) {
  int r0 = blockIdx.x * 32;
  int wv = __builtin_amdgcn_readfirstlane(threadIdx.x >> 6);
  int lane = threadIdx.x & 63;
  int u2 = lane * 2;
  int rbase = r0 + wv * 8;
  float acc[8][2];
#pragma unroll
  for (int i = 0; i < 8; i++) { acc[i][0] = 0.f; acc[i][1] = 0.f; }
#pragma unroll 2
  for (int k2 = 0; k2 < 128; ++k2) {
    int m_lo = 8 * (k2 >> 2) + (k2 & 3);
    float2 wh0 = *(const float2*)(Wd + (size_t)m_lo * Tc + u2);
    float2 wh1 = *(const float2*)(Wd + (size_t)(m_lo + 4) * Tc + u2);
    float2 wc0 = *(const float2*)(Wd + (size_t)(Mc + 2 * k2) * Tc + u2);
    float2 wc1 = *(const float2*)(Wd + (size_t)(Mc + 2 * k2 + 1) * Tc + u2);
#pragma unroll
    for (int i = 0; i < 8; i++) {
      unsigned hraw = ~Hxu[(size_t)(rbase + i) * 128 + 16384 + k2];  // slot t+1
      __half2 hv = __builtin_bit_cast(__half2, hraw);
      __half2 cv = Cx2[(size_t)(rbase + i) * 128 + k2];
      float hlo = __low2float(hv), hhi = __high2float(hv);
      float clo = __low2float(cv), chi = __high2float(cv);
      acc[i][0] += hlo * wh0.x + hhi * wh1.x + clo * wc0.x + chi * wc1.x;
      acc[i][1] += hlo * wh0.y + hhi * wh1.y + clo * wc0.y + chi * wc1.y;
    }
  }
  float bw0 = bW[u2], bw1 = bW[u2 + 1];
#pragma unroll
  for (int i = 0; i < 8; i++) {
    float2 o; o.x = acc[i][0] + bw0; o.y = acc[i][1] + bw1;
    *(float2*)(Wall + (size_t)(rbase + i) * Tc + u2) = o;
  }
}

// ---------------------------------------------------------------------------
// k_attn: logits_n = sum_u (-2 v_u) / (A_u * P_un + 1); softmax; out = X*alpha
// ---------------------------------------------------------------------------
__global__ void k_attn(const float* __restrict__ Wall, const float* __restrict__ PX,
                       const float* __restrict__ vd, const float* __restrict__ X,
                       float* __restrict__ out) {
  __shared__ float4 av[Nc];
  __shared__ float v2s[Nc];
  __shared__ float red[2][8];
  int b = blockIdx.x & 127, tq = blockIdx.x >> 7;
  int n = threadIdx.x;           // 0..127
  int wv = n >> 6;
  float4 a;
  a.x = __expf(2.f * Wall[((size_t)(tq * 4 + 0) * Bc + b) * Tc + n]);
  a.y = __expf(2.f * Wall[((size_t)(tq * 4 + 1) * Bc + b) * Tc + n]);
  a.z = __expf(2.f * Wall[((size_t)(tq * 4 + 2) * Bc + b) * Tc + n]);
  a.w = __expf(2.f * Wall[((size_t)(tq * 4 + 3) * Bc + b) * Tc + n]);
  av[n] = a;
  v2s[n] = -2.f * vd[n];
  __syncthreads();
  const float* Pb = PX + (size_t)b * Tc * Nc;
  float e0 = 0.f, e1 = 0.f, e2 = 0.f, e3 = 0.f;
#pragma unroll 4
  for (int u = 0; u < Tc; ++u) {
    float P = Pb[(size_t)u * Nc + n];
    float4 au = av[u];
    float v2 = v2s[u];
    e0 = fmaf(v2, frcp(fmaf(au.x, P, 1.f)), e0);
    e1 = fmaf(v2, frcp(fmaf(au.y, P, 1.f)), e1);
    e2 = fmaf(v2, frcp(fmaf(au.z, P, 1.f)), e2);
    e3 = fmaf(v2, frcp(fmaf(au.w, P, 1.f)), e3);
  }
  float m0 = e0, m1 = e1, m2 = e2, m3 = e3;
#pragma unroll
  for (int off = 32; off > 0; off >>= 1) {
    m0 = fmaxf(m0, __shfl_xor(m0, off));
    m1 = fmaxf(m1, __shfl_xor(m1, off));
    m2 = fmaxf(m2, __shfl_xor(m2, off));
    m3 = fmaxf(m3, __shfl_xor(m3, off));
  }
  if ((n & 63) == 0) {
    red[wv][0] = m0; red[wv][1] = m1; red[wv][2] = m2; red[wv][3] = m3;
  }
  __syncthreads();
  m0 = fmaxf(red[0][0], red[1][0]);
  m1 = fmaxf(red[0][1], red[1][1]);
  m2 = fmaxf(red[0][2], red[1][2]);
  m3 = fmaxf(red[0][3], red[1][3]);
  float x0 = __expf(e0 - m0);
  float x1 = __expf(e1 - m1);
  float x2 = __expf(e2 - m2);
  float x3 = __expf(e3 - m3);
  float s0 = x0, s1 = x1, s2 = x2, s3 = x3;
#pragma unroll
  for (int off = 32; off > 0; off >>= 1) {
    s0 += __shfl_xor(s0, off);
    s1 += __shfl_xor(s1, off);
    s2 += __shfl_xor(s2, off);
    s3 += __shfl_xor(s3, off);
  }
  if ((n & 63) == 0) {
    red[wv][4] = s0; red[wv][5] = s1; red[wv][6] = s2; red[wv][7] = s3;
  }
  __syncthreads();
  s0 = red[0][4] + red[1][4];
  s1 = red[0][5] + red[1][5];
  s2 = red[0][6] + red[1][6];
  s3 = red[0][7] + red[1][7];
  size_t xi0 = ((size_t)b * Tc + tq * 4) * Nc + n;
  out[xi0]            = X[xi0]            * (x0 * frcp(s0));
  out[xi0 + Nc]       = X[xi0 + Nc]       * (x1 * frcp(s1));
  out[xi0 + 2 * Nc]   = X[xi0 + 2 * Nc]   * (x2 * frcp(s2));
  out[xi0 + 3 * Nc]   = X[xi0 + 3 * Nc]   * (x3 * frcp(s3));
}

extern "C" void kernel_launch(void* const* d_in, const int* in_sizes, int n_in,
                              void* d_out, int out_size, void* d_ws, size_t ws_size,
                              hipStream_t stream) {
  (void)in_sizes; (void)n_in; (void)out_size; (void)ws_size;
  const float* X  = (const float*)d_in[0];
  const float* h0 = (const float*)d_in[1];
  const float* s0 = (const float*)d_in[2];
  const float* Wx = (const float*)d_in[3];
  const float* Wh = (const float*)d_in[4];
  const float* bb = (const float*)d_in[5];
  const float* Wd = (const float*)d_in[6];
  const float* bW = (const float*)d_in[7];
  const float* Ud = (const float*)d_in[8];
  const float* bU = (const float*)d_in[9];
  const float* vd = (const float*)d_in[10];
  // d_in[11] = bv: softmax(x + const) == softmax(x), no effect on output.
  float* out = (float*)d_out;
  float* ws = (float*)d_ws;

  float* PX       = ws;                            //  2,097,152 f
  unsigned* hx2   = (unsigned*)(PX + 2097152);     // 129*16384 u32 (~h pairs)
  __half* cx      = (__half*)(hx2 + 129 * 16384);  // 128*32768 halves
  float* Wall     = (float*)(cx + 128 * 32768);    //  2,097,152 f
  __half* wht     = (__half*)(Wall + 2097152);     //   262,144 halves
  __half* wxt     = wht + 262144;                  //   131,072 halves
  __half* xtp     = wxt + 131072;                  // 2,097,152 halves
  unsigned* flags = (unsigned*)(xtp + 2097152);    // 16512 flags + 32 xcdtab
  // total ~39 MB

  k_prep<<<13121, 256, 0, stream>>>(Wh, Wx, X, h0, wht, wxt, xtp, hx2, flags);
  k_ux<<<Bc, 256, 0, stream>>>(X, Ud, bU, PX);
  k_scan<<<32, 512, 0, stream>>>(wht, wxt, xtp, hx2, cx, s0, bb, flags);
  k_wall2<<<(Tc * Bc) / 32, 256, 0, stream>>>(hx2, (const __half2*)cx, Wd, bW, Wall);
  k_attn<<<Bc * 32, 128, 0, stream>>>(Wall, PX, vd, X, out);
}

// Round 15
// 580.746 us; speedup vs baseline: 1.1812x; 1.1104x over previous
//
#include <hip/hip_runtime.h>
#include <hip/hip_fp16.h>

// Problem dims (fixed)
#define Bc 128   // batch
#define Tc 128   // timesteps
#define Nc 128   // driving series
#define Mc 256   // hidden
#define G4 1024  // 4*M

typedef _Float16 half8 __attribute__((ext_vector_type(8)));
typedef float f32x4 __attribute__((ext_vector_type(4)));
typedef unsigned u32x4 __attribute__((ext_vector_type(4)));

__device__ __forceinline__ float frcp(float x) {
#if __has_builtin(__builtin_amdgcn_rcpf)
  return __builtin_amdgcn_rcpf(x);
#else
  return 1.f / x;
#endif
}
__device__ __forceinline__ float fsig(float x) { return frcp(1.f + __expf(-x)); }
__device__ __forceinline__ float ftanh(float x) {
  float t = __expf(2.f * x);
  return 1.f - 2.f * frcp(t + 1.f);
}

// gfx950: offset:N must precede cache flags
#define LDX4CC(dst, ptr, OFF) \
  asm volatile("global_load_dwordx4 %0, %1, off offset:" #OFF " sc0 sc1" \
               : "=v"(dst) : "v"(ptr))
#define LDX4P(dst, ptr, OFF) \
  asm volatile("global_load_dwordx4 %0, %1, off offset:" #OFF \
               : "=v"(dst) : "v"(ptr))
#define ATOMSW(ptr, v_) \
  asm volatile("global_atomic_swap %0, %1, off" :: "v"(ptr), "v"(v_) : "memory")
#define STDWP(ptr, v_) \
  asm volatile("global_store_dword %0, %1, off" :: "v"(ptr), "v"(v_) : "memory")
#define VMCNT0 do { asm volatile("s_waitcnt vmcnt(0)" ::: "memory"); \
                    __builtin_amdgcn_sched_barrier(0); } while (0)
#define VMCNT4 do { asm volatile("s_waitcnt vmcnt(4)" ::: "memory"); \
                    __builtin_amdgcn_sched_barrier(0); } while (0)

// ---------------------------------------------------------------------------
// k_prep (5441 blocks x 256):
//  [0,512)     : Wh -> wht fp16 A-frags (cols j'=4m+g, k-pairs (r2, r2+4))
//  [512,768)   : Wx -> wxt fp16 A-frags (same col perm, natural k)
//  [768,832)   : hx2[0] = ~pack(fp16(h0))
//  [832,1344)  : zero hx2[1..128] (vectorized x16 u32)
//  [1344,5440) : X -> xtp fp16 B-frags [t][b][kt][lg][r2][2], natural k
//  5440        : zero flags + xcdtab
// ---------------------------------------------------------------------------
__global__ void k_prep(const float* __restrict__ Wh, const float* __restrict__ Wx,
                       const float* __restrict__ X, const float* __restrict__ h0,
                       __half* __restrict__ wht, __half* __restrict__ wxt,
                       __half* __restrict__ xtp, unsigned* __restrict__ hx2,
                       unsigned* __restrict__ flags) {
  int bid = blockIdx.x;
  if (bid < 512) {
    int i = bid * 256 + threadIdx.x;       // u32 index in [0, 131072)
    int jt = i >> 11;
    int rem = i & 2047;
    int kt = rem >> 8;
    int rem2 = rem & 255;
    int lane = rem2 >> 2;
    int r2 = rem2 & 3;
    int jp = jt * 16 + (lane & 15);        // permuted col j'
    int g = jp & 3, mcol = jp >> 2;
    int j = g * 256 + mcol;                // original Wh column
    int mk0 = kt * 32 + (lane >> 4) * 8 + r2;   // k-pair (r2, r2+4)
    wht[(size_t)i * 2]     = __float2half(Wh[(size_t)mk0 * G4 + j]);
    wht[(size_t)i * 2 + 1] = __float2half(Wh[(size_t)(mk0 + 4) * G4 + j]);
  } else if (bid < 768) {
    int i = (bid - 512) * 256 + threadIdx.x;   // u32 index in [0, 65536)
    int jt = i >> 10;
    int rem = i & 1023;
    int kt = rem >> 8;
    int rem2 = rem & 255;
    int lane = rem2 >> 2;
    int r2 = rem2 & 3;
    int jp = jt * 16 + (lane & 15);
    int g = jp & 3, mcol = jp >> 2;
    int j = g * 256 + mcol;
    int n0 = kt * 32 + (lane >> 4) * 8 + 2 * r2;   // natural k order
    wxt[(size_t)i * 2]     = __float2half(Wx[(size_t)n0 * G4 + j]);
    wxt[(size_t)i * 2 + 1] = __float2half(Wx[(size_t)(n0 + 1) * G4 + j]);
  } else if (bid < 832) {
    int idx = (bid - 768) * 256 + threadIdx.x;   // 0..16383
    int b = idx >> 7, i = idx & 127;
    int a = i >> 2, d = i & 3;
    unsigned lo = __half_as_ushort(__float2half(h0[(size_t)b * Mc + 8 * a + d]));
    unsigned hi = __half_as_ushort(__float2half(h0[(size_t)b * Mc + 8 * a + d + 4]));
    hx2[idx] = ~(lo | (hi << 16));
  } else if (bid < 1344) {
    int idx = (bid - 832) * 256 + threadIdx.x;   // 0..131071 (x16 u32 each)
    u32x4 z = {0u, 0u, 0u, 0u};
    u32x4* p = (u32x4*)(hx2 + 16384) + (size_t)idx * 4;
    p[0] = z; p[1] = z; p[2] = z; p[3] = z;
  } else if (bid < 5440) {
    int i = (bid - 1344) * 256 + threadIdx.x;    // u32 index in [0, 1048576)
    int t = i >> 13;
    int rem = i & 8191;
    int b = rem >> 6;
    int rem2 = rem & 63;
    int kt = rem2 >> 4;
    int r = rem2 & 15;
    int lg = r >> 2, r2 = r & 3;
    int n0 = kt * 32 + lg * 8 + 2 * r2;          // natural k order
    const float* xr = X + ((size_t)b * Tc + t) * Nc;
    xtp[(size_t)i * 2]     = __float2half(xr[n0]);
    xtp[(size_t)i * 2 + 1] = __float2half(xr[n0 + 1]);
  } else {
    for (int i = threadIdx.x; i < 16544; i += 256) flags[i] = 0u;
  }
}

// ---------------------------------------------------------------------------
// scan_body: r11-proven sync + fused x@Wx MFMAs + one-step-ahead xt prefetch.
// FAST: plain L2 exchange; poll = lane0 atomic_or on one flag line; publish =
// h store -> issue xt(t+1) -> vmcnt(4) (drains the store only, m135 oldest-
// first) -> barrier -> atomic_add flag -> c stores. The xt prefetch flies
// through barrier+flag+poll so the next poll is near-clean (r14's 900cy
// poll-side xt stall removed). SLOW: r10's sc0sc1 data-is-flag.
// ---------------------------------------------------------------------------
template <bool FAST>
__device__ __forceinline__ void scan_body(
    const __half* __restrict__ wht, const __half* __restrict__ wxt,
    const __half* __restrict__ xtp,
    unsigned* __restrict__ hx2, __half* __restrict__ cx,
    const float* __restrict__ s0, const float* __restrict__ bb,
    unsigned* __restrict__ flags,
    int q, int grp, int tid, int lane, int lg, int b, int jt0, int m0) {
  half8 A0[8], A1[8];
#pragma unroll
  for (int kt = 0; kt < 8; ++kt) {
    A0[kt] = *(const half8*)(wht + ((size_t)(jt0 * 8 + kt) * 64 + lane) * 8);
    A1[kt] = *(const half8*)(wht + ((size_t)((jt0 + 1) * 8 + kt) * 64 + lane) * 8);
  }
  half8 Ax0[4], Ax1[4];
#pragma unroll
  for (int kt = 0; kt < 4; ++kt) {
    Ax0[kt] = *(const half8*)(wxt + ((size_t)(jt0 * 4 + kt) * 64 + lane) * 8);
    Ax1[kt] = *(const half8*)(wxt + ((size_t)((jt0 + 1) * 4 + kt) * 64 + lane) * 8);
  }
  f32x4 binit0, binit1;
  binit0[0] = bb[m0];       binit0[1] = bb[256 + m0];
  binit0[2] = bb[512 + m0]; binit0[3] = bb[768 + m0];
  binit1[0] = bb[m0 + 4];       binit1[1] = bb[256 + m0 + 4];
  binit1[2] = bb[512 + m0 + 4]; binit1[3] = bb[768 + m0 + 4];

  float c0 = s0[(size_t)b * Mc + m0];
  float c1 = s0[(size_t)b * Mc + m0 + 4];

  const char* hq = (const char*)hx2 + ((size_t)b * 128 + lg * 4) * 4;
  char*       hs = (char*)hx2 + ((size_t)16384 + b * 128 + jt0 * 2 + lg) * 4;
  const char* xt = (const char*)xtp + (size_t)b * 256 + lg * 16;
  __half*      cq = cx + (size_t)b * Mc;
  unsigned* flgp = flags + (size_t)grp * 129 * 16;

  f32x4 braw[8];
  f32x4 bxA0, bxA1, bxA2, bxA3;   // current step's x B-frags
  f32x4 bxB0, bxB1, bxB2, bxB3;   // prefetch for t+1

  // prologue: drain compiler VMEM, then load x frags for t=0
  asm volatile("s_waitcnt vmcnt(0)" ::: "memory");
  __builtin_amdgcn_sched_barrier(0);
  LDX4P(bxA0, xt, 0); LDX4P(bxA1, xt, 64);
  LDX4P(bxA2, xt, 128); LDX4P(bxA3, xt, 192);

#pragma unroll 1
  for (int t = 0; t < 128; ++t) {
    asm volatile("" : "+v"(A0[0]), "+v"(A0[1]), "+v"(A0[2]), "+v"(A0[3]),
                      "+v"(A0[4]), "+v"(A0[5]), "+v"(A0[6]), "+v"(A0[7]));
    asm volatile("" : "+v"(A1[0]), "+v"(A1[1]), "+v"(A1[2]), "+v"(A1[3]),
                      "+v"(A1[4]), "+v"(A1[5]), "+v"(A1[6]), "+v"(A1[7]));
    asm volatile("" : "+v"(Ax0[0]), "+v"(Ax0[1]), "+v"(Ax0[2]), "+v"(Ax0[3]),
                      "+v"(Ax1[0]), "+v"(Ax1[1]), "+v"(Ax1[2]), "+v"(Ax1[3]),
                      "+v"(binit0), "+v"(binit1));

    if (FAST) {
      if (t > 0) {
        unsigned ret = 0u;
#pragma unroll 1
        do {
          if (lane == 0)
            asm volatile("global_atomic_or %0, %1, %2, off sc0\n\t"
                         "s_waitcnt vmcnt(0)"
                         : "=v"(ret) : "v"(flgp + t * 16), "v"(0u) : "memory");
          ret = __builtin_amdgcn_readfirstlane(ret);
        } while (ret < 4u);
        __builtin_amdgcn_sched_barrier(0);
      }
      LDX4P(braw[0], hq, 0);   LDX4P(braw[1], hq, 64);
      LDX4P(braw[2], hq, 128); LDX4P(braw[3], hq, 192);
      LDX4P(braw[4], hq, 256); LDX4P(braw[5], hq, 320);
      LDX4P(braw[6], hq, 384); LDX4P(braw[7], hq, 448);
      VMCNT0;
    } else {
      LDX4CC(braw[0], hq, 0);   LDX4CC(braw[1], hq, 64);
      LDX4CC(braw[2], hq, 128); LDX4CC(braw[3], hq, 192);
      LDX4CC(braw[4], hq, 256); LDX4CC(braw[5], hq, 320);
      LDX4CC(braw[6], hq, 384); LDX4CC(braw[7], hq, 448);
      for (;;) {
        VMCNT0;
        unsigned mn = 0xFFFFFFFFu;
#pragma unroll
        for (int kt = 0; kt < 8; ++kt) {
          u32x4 u = __builtin_bit_cast(u32x4, braw[kt]);
          mn = min(mn, min(min(u.x, u.y), min(u.z, u.w)));
        }
        if (__builtin_expect(mn != 0u, 1)) break;
        LDX4CC(braw[0], hq, 0);   LDX4CC(braw[1], hq, 64);
        LDX4CC(braw[2], hq, 128); LDX4CC(braw[3], hq, 192);
        LDX4CC(braw[4], hq, 256); LDX4CC(braw[5], hq, 320);
        LDX4CC(braw[6], hq, 384); LDX4CC(braw[7], hq, 448);
      }
    }

    f32x4 acc0 = binit0, acc1 = binit1;
    {
      half8 B0 = __builtin_bit_cast(half8, bxA0);
      half8 B1 = __builtin_bit_cast(half8, bxA1);
      half8 B2 = __builtin_bit_cast(half8, bxA2);
      half8 B3 = __builtin_bit_cast(half8, bxA3);
      acc0 = __builtin_amdgcn_mfma_f32_16x16x32_f16(Ax0[0], B0, acc0, 0, 0, 0);
      acc1 = __builtin_amdgcn_mfma_f32_16x16x32_f16(Ax1[0], B0, acc1, 0, 0, 0);
      acc0 = __builtin_amdgcn_mfma_f32_16x16x32_f16(Ax0[1], B1, acc0, 0, 0, 0);
      acc1 = __builtin_amdgcn_mfma_f32_16x16x32_f16(Ax1[1], B1, acc1, 0, 0, 0);
      acc0 = __builtin_amdgcn_mfma_f32_16x16x32_f16(Ax0[2], B2, acc0, 0, 0, 0);
      acc1 = __builtin_amdgcn_mfma_f32_16x16x32_f16(Ax1[2], B2, acc1, 0, 0, 0);
      acc0 = __builtin_amdgcn_mfma_f32_16x16x32_f16(Ax0[3], B3, acc0, 0, 0, 0);
      acc1 = __builtin_amdgcn_mfma_f32_16x16x32_f16(Ax1[3], B3, acc1, 0, 0, 0);
    }
#pragma unroll
    for (int kt = 0; kt < 8; ++kt) {
      u32x4 u = ~__builtin_bit_cast(u32x4, braw[kt]);
      half8 Bf = __builtin_bit_cast(half8, u);
      acc0 = __builtin_amdgcn_mfma_f32_16x16x32_f16(A0[kt], Bf, acc0, 0, 0, 0);
      acc1 = __builtin_amdgcn_mfma_f32_16x16x32_f16(A1[kt], Bf, acc1, 0, 0, 0);
    }
    float i0 = fsig(acc0[0]), f0 = fsig(acc0[1]);
    float g0 = ftanh(acc0[2]), o0 = fsig(acc0[3]);
    c0 = f0 * c0 + i0 * g0;
    float h0v = o0 * ftanh(c0);
    float i1 = fsig(acc1[0]), f1 = fsig(acc1[1]);
    float g1 = ftanh(acc1[2]), o1 = fsig(acc1[3]);
    c1 = f1 * c1 + i1 * g1;
    float h1v = o1 * ftanh(c1);

    unsigned pk = (unsigned)__half_as_ushort(__float2half(h0v)) |
                  ((unsigned)__half_as_ushort(__float2half(h1v)) << 16);
    if (FAST) {
      STDWP(hs, ~pk);                      // h store (oldest outstanding)
      if (t < 127) {
        const char* xtn = xt + 32768;      // prefetch xt for t+1
        LDX4P(bxB0, xtn, 0); LDX4P(bxB1, xtn, 64);
        LDX4P(bxB2, xtn, 128); LDX4P(bxB3, xtn, 192);
        VMCNT4;                            // drains exactly the h store
      } else {
        VMCNT0;
      }
      __syncthreads();
      if (tid == 0)
        asm volatile("global_atomic_add %0, %1, off"
                     :: "v"(flgp + (t + 1) * 16), "v"(1u) : "memory");
      cq[m0]     = __float2half(c0);
      cq[m0 + 4] = __float2half(c1);
      bxA0 = bxB0; bxA1 = bxB1; bxA2 = bxB2; bxA3 = bxB3;
    } else {
      ATOMSW(hs, ~pk);
      cq[m0]     = __float2half(c0);
      cq[m0 + 4] = __float2half(c1);
      if (t < 127) {
        const char* xtn = xt + 32768;
        LDX4P(bxA0, xtn, 0); LDX4P(bxA1, xtn, 64);
        LDX4P(bxA2, xtn, 128); LDX4P(bxA3, xtn, 192);
      }
    }

    hq += 65536; hs += 65536; xt += 32768; cq += Bc * Mc;
  }
}

// ---------------------------------------------------------------------------
// k_scan: 160 blocks x 512 threads. Blocks 0..31 = persistent LSTM scan
// (r11 sync + fused x@Wx + xt prefetch). Blocks 32..159 = k_ux work
// (PX = exp(2*(X@Ud + bU))) on otherwise-idle CUs — hidden under the scan.
// ---------------------------------------------------------------------------
__global__ __launch_bounds__(512, 1)
void k_scan(const __half* __restrict__ wht, const __half* __restrict__ wxt,
            const __half* __restrict__ xtp,
            unsigned* __restrict__ hx2, __half* __restrict__ cx,
            const float* __restrict__ s0, const float* __restrict__ bb,
            unsigned* __restrict__ flags,
            const float* __restrict__ X, const float* __restrict__ Ud,
            const float* __restrict__ bU, float* __restrict__ PX) {
  __shared__ float Xl[Tc][Nc];          // used by ux blocks only (64KB)
  __shared__ int s_fast;
  int bid = blockIdx.x;
  int tid = threadIdx.x;

  if (bid >= 32) {
    // ---- k_ux body (512 threads) ----
    int b = bid - 32;
    const float* Xb = X + (size_t)b * Tc * Nc;
    for (int i = tid; i < Tc * Nc; i += 512) Xl[i >> 7][i & 127] = Xb[i];
    __syncthreads();
    int n = tid & 127;
    int uh = __builtin_amdgcn_readfirstlane(tid >> 7);  // 0..3, wave-uniform
    for (int u0 = uh * 32; u0 < uh * 32 + 32; u0 += 8) {
      float acc[8];
#pragma unroll
      for (int i = 0; i < 8; i++) acc[i] = 0.f;
      for (int tt = 0; tt < Tc; ++tt) {
        float xv = Xl[tt][n];
#pragma unroll
        for (int i = 0; i < 8; i++) acc[i] += xv * Ud[tt * Tc + u0 + i];
      }
#pragma unroll
      for (int i = 0; i < 8; i++)
        PX[((size_t)b * Tc + (u0 + i)) * Nc + n] = __expf(2.f * (acc[i] + bU[u0 + i]));
    }
    return;
  }

  // ---- scan blocks ----
  int q = bid >> 3, grp = bid & 7;
  int lane = tid & 63;
  int lb = lane & 15, lg = lane >> 4;
  int b = grp * 16 + lb;
  int jt0 = q * 16 + (tid >> 6) * 2;
  int m0 = jt0 * 4 + lg;

  unsigned* xcdtab = flags + 16512;
  if (tid == 0) {
    unsigned xcd;
    asm volatile("s_getreg_b32 %0, hwreg(HW_REG_XCC_ID)" : "=s"(xcd));
    asm volatile("global_store_dword %0, %1, off sc0 sc1"
                 :: "v"(xcdtab + bid), "v"(xcd + 1u) : "memory");
    unsigned ref = 0; int fast = 1;
#pragma unroll 1
    for (int k = 0; k < 4; ++k) {
      unsigned v;
      do {
        asm volatile("global_load_dword %0, %1, off sc0 sc1\n\t"
                     "s_waitcnt vmcnt(0)"
                     : "=v"(v) : "v"(xcdtab + (k * 8 + grp)) : "memory");
      } while (v == 0u);
      if (k == 0) ref = v; else fast &= (v == ref) ? 1 : 0;
    }
    s_fast = fast;
  }
  __syncthreads();

  if (s_fast)
    scan_body<true>(wht, wxt, xtp, hx2, cx, s0, bb, flags, q, grp, tid, lane, lg, b, jt0, m0);
  else
    scan_body<false>(wht, wxt, xtp, hx2, cx, s0, bb, flags, q, grp, tid, lane, lg, b, jt0, m0);
}

// ---------------------------------------------------------------------------
// k_attn (merged wall+attn): block (b,tq) computes its 4 Wall rows from
// hx2/cx + Wd (same FLOPs as old k_wall2, zero redundancy: 4096 x 4 = all
// 16384 rows), then softmax/scale. Kills the 16MB Wall round-trip + launch.
// ---------------------------------------------------------------------------
__global__ void k_attn(const unsigned* __restrict__ Hxu, const unsigned* __restrict__ Cxu,
                       const float* __restrict__ Wd, const float* __restrict__ bW,
                       const float* __restrict__ PX, const float* __restrict__ vd,
                       const float* __restrict__ X, float* __restrict__ out) {
  __shared__ unsigned hl[4][Nc];
  __shared__ unsigned cl[4][Nc];
  __shared__ float4 av[Nc];
  __shared__ float v2s[Nc];
  __shared__ float red[2][8];
  int b = blockIdx.x & 127, tq = blockIdx.x >> 7;
  int n = threadIdx.x;           // 0..127
  int wv = n >> 6;
#pragma unroll
  for (int k = 0; k < 4; ++k) {
    int t = tq * 4 + k;
    hl[k][n] = Hxu[(size_t)(t + 1) * 16384 + b * 128 + n];
    cl[k][n] = Cxu[((size_t)t * 128 + b) * 128 + n];
  }
  v2s[n] = -2.f * vd[n];
  __syncthreads();
  // wall rows: a_k = bW[n] + sum_k2 h/c contributions (fully scalar state)
  float a0 = bW[n], a1 = bW[n], a2 = bW[n], a3 = bW[n];
#pragma unroll 2
  for (int k2 = 0; k2 < 128; ++k2) {
    int m_lo = 8 * (k2 >> 2) + (k2 & 3);
    float wh0 = Wd[(size_t)m_lo * Tc + n];
    float wh1 = Wd[(size_t)(m_lo + 4) * Tc + n];
    float wc0 = Wd[(size_t)(Mc + 2 * k2) * Tc + n];
    float wc1 = Wd[(size_t)(Mc + 2 * k2 + 1) * Tc + n];
    {
      __half2 hv = __builtin_bit_cast(__half2, ~hl[0][k2]);
      __half2 cv = __builtin_bit_cast(__half2, cl[0][k2]);
      a0 += __low2float(hv) * wh0 + __high2float(hv) * wh1 +
            __low2float(cv) * wc0 + __high2float(cv) * wc1;
    }
    {
      __half2 hv = __builtin_bit_cast(__half2, ~hl[1][k2]);
      __half2 cv = __builtin_bit_cast(__half2, cl[1][k2]);
      a1 += __low2float(hv) * wh0 + __high2float(hv) * wh1 +
            __low2float(cv) * wc0 + __high2float(cv) * wc1;
    }
    {
      __half2 hv = __builtin_bit_cast(__half2, ~hl[2][k2]);
      __half2 cv = __builtin_bit_cast(__half2, cl[2][k2]);
      a2 += __low2float(hv) * wh0 + __high2float(hv) * wh1 +
            __low2float(cv) * wc0 + __high2float(cv) * wc1;
    }
    {
      __half2 hv = __builtin_bit_cast(__half2, ~hl[3][k2]);
      __half2 cv = __builtin_bit_cast(__half2, cl[3][k2]);
      a3 += __low2float(hv) * wh0 + __high2float(hv) * wh1 +
            __low2float(cv) * wc0 + __high2float(cv) * wc1;
    }
  }
  float4 a;
  a.x = __expf(2.f * a0); a.y = __expf(2.f * a1);
  a.z = __expf(2.f * a2); a.w = __expf(2.f * a3);
  av[n] = a;
  __syncthreads();
  const float* Pb = PX + (size_t)b * Tc * Nc;
  float e0 = 0.f, e1 = 0.f, e2 = 0.f, e3 = 0.f;
#pragma unroll 4
  for (int u = 0; u < Tc; ++u) {
    float P = Pb[(size_t)u * Nc + n];
    float4 au = av[u];
    float v2 = v2s[u];
    e0 = fmaf(v2, frcp(fmaf(au.x, P, 1.f)), e0);
    e1 = fmaf(v2, frcp(fmaf(au.y, P, 1.f)), e1);
    e2 = fmaf(v2, frcp(fmaf(au.z, P, 1.f)), e2);
    e3 = fmaf(v2, frcp(fmaf(au.w, P, 1.f)), e3);
  }
  float m0 = e0, m1 = e1, m2 = e2, m3 = e3;
#pragma unroll
  for (int off = 32; off > 0; off >>= 1) {
    m0 = fmaxf(m0, __shfl_xor(m0, off));
    m1 = fmaxf(m1, __shfl_xor(m1, off));
    m2 = fmaxf(m2, __shfl_xor(m2, off));
    m3 = fmaxf(m3, __shfl_xor(m3, off));
  }
  if ((n & 63) == 0) {
    red[wv][0] = m0; red[wv][1] = m1; red[wv][2] = m2; red[wv][3] = m3;
  }
  __syncthreads();
  m0 = fmaxf(red[0][0], red[1][0]);
  m1 = fmaxf(red[0][1], red[1][1]);
  m2 = fmaxf(red[0][2], red[1][2]);
  m3 = fmaxf(red[0][3], red[1][3]);
  float x0 = __expf(e0 - m0);
  float x1 = __expf(e1 - m1);
  float x2 = __expf(e2 - m2);
  float x3 = __expf(e3 - m3);
  float s0 = x0, s1 = x1, s2 = x2, s3 = x3;
#pragma unroll
  for (int off = 32; off > 0; off >>= 1) {
    s0 += __shfl_xor(s0, off);
    s1 += __shfl_xor(s1, off);
    s2 += __shfl_xor(s2, off);
    s3 += __shfl_xor(s3, off);
  }
  if ((n & 63) == 0) {
    red[wv][4] = s0; red[wv][5] = s1; red[wv][6] = s2; red[wv][7] = s3;
  }
  __syncthreads();
  s0 = red[0][4] + red[1][4];
  s1 = red[0][5] + red[1][5];
  s2 = red[0][6] + red[1][6];
  s3 = red[0][7] + red[1][7];
  size_t xi0 = ((size_t)b * Tc + tq * 4) * Nc + n;
  out[xi0]            = X[xi0]            * (x0 * frcp(s0));
  out[xi0 + Nc]       = X[xi0 + Nc]       * (x1 * frcp(s1));
  out[xi0 + 2 * Nc]   = X[xi0 + 2 * Nc]   * (x2 * frcp(s2));
  out[xi0 + 3 * Nc]   = X[xi0 + 3 * Nc]   * (x3 * frcp(s3));
}

extern "C" void kernel_launch(void* const* d_in, const int* in_sizes, int n_in,
                              void* d_out, int out_size, void* d_ws, size_t ws_size,
                              hipStream_t stream) {
  (void)in_sizes; (void)n_in; (void)out_size; (void)ws_size;
  const float* X  = (const float*)d_in[0];
  const float* h0 = (const float*)d_in[1];
  const float* s0 = (const float*)d_in[2];
  const float* Wx = (const float*)d_in[3];
  const float* Wh = (const float*)d_in[4];
  const float* bb = (const float*)d_in[5];
  const float* Wd = (const float*)d_in[6];
  const float* bW = (const float*)d_in[7];
  const float* Ud = (const float*)d_in[8];
  const float* bU = (const float*)d_in[9];
  const float* vd = (const float*)d_in[10];
  // d_in[11] = bv: softmax(x + const) == softmax(x), no effect on output.
  float* out = (float*)d_out;
  float* ws = (float*)d_ws;

  float* PX       = ws;                            //  2,097,152 f
  unsigned* hx2   = (unsigned*)(PX + 2097152);     // 129*16384 u32 (~h pairs)
  unsigned* cxu   = hx2 + 129 * 16384;             // 128*16384 u32 (c half2)
  __half* wht     = (__half*)(cxu + 128 * 16384);  //   262,144 halves
  __half* wxt     = wht + 262144;                  //   131,072 halves
  __half* xtp     = wxt + 131072;                  // 2,097,152 halves
  unsigned* flags = (unsigned*)(xtp + 2097152);    // 16512 flags + 32 xcdtab
  // total ~31 MB

  k_prep<<<5441, 256, 0, stream>>>(Wh, Wx, X, h0, wht, wxt, xtp, hx2, flags);
  k_scan<<<160, 512, 0, stream>>>(wht, wxt, xtp, hx2, (__half*)cxu, s0, bb, flags,
                                  X, Ud, bU, PX);
  k_attn<<<Bc * 32, 128, 0, stream>>>(hx2, cxu, Wd, bW, PX, vd, X, out);
}